// Round 1
// baseline (474.063 us; speedup 1.0000x reference)
//
#include <hip/hip_runtime.h>
#include <math.h>

#define DIN 50176
#define BSZ 32
#define FEATN 128
#define KQ 512
#define NN 513      // KQ + 1
#define NE (NN * 5) // 2565 edges per batch
#define MM 0.999f
#define ONE_MM 0.001f
#define TT 0.07f

// ---------------- K1: fused dual GEMM, split-K, deterministic partials ----------------
// z_q[b][c] = sum_k Xq[b][k] * Wq[k][c]
// z_k[b][c] = sum_k Xk[b][k] * (M*Wk[k][c] + (1-M)*Wq[k][c])
// grid: nblk blocks x 256 threads; thread = (c = tid&127, r = tid>>7 in {0,1})
// Each block covers `chunk` consecutive k. X values are wave-uniform -> scalar loads.
__global__ __launch_bounds__(256) void k_dualgemm(
    const float* __restrict__ Xq, const float* __restrict__ Xk,
    const float* __restrict__ Wq, const float* __restrict__ Wk,
    float* __restrict__ part, int chunk) {
  const int tid = threadIdx.x;
  const int c = tid & 127;
  const int r = tid >> 7;       // wave-uniform (128-thread groups = 2 waves)
  const int blk = blockIdx.x;
  float accq[32], acck[32];
#pragma unroll
  for (int b = 0; b < 32; ++b) { accq[b] = 0.f; acck[b] = 0.f; }
  const int k0 = blk * chunk + r;
  const int iters = chunk >> 1;
  for (int i = 0; i < iters; ++i) {
    const int ku = __builtin_amdgcn_readfirstlane(k0 + 2 * i);
    const float wq = Wq[ku * FEATN + c];
    const float wk = Wk[ku * FEATN + c];
    const float w2 = fmaf(MM, wk, ONE_MM * wq);
    const float* xq = Xq + ku;
    const float* xk = Xk + ku;
#pragma unroll
    for (int b = 0; b < 32; ++b) {
      accq[b] = fmaf(wq, xq[b * DIN], accq[b]);   // uniform addr -> s_load
      acck[b] = fmaf(w2, xk[b * DIN], acck[b]);
    }
  }
  // Reduce over r (2 copies) via LDS, write 8192 partials per block.
  __shared__ float red[8 * 256];
#pragma unroll
  for (int g = 0; g < 8; ++g) {
#pragma unroll
    for (int s = 0; s < 8; ++s) {
      const int v = g * 8 + s;
      red[s * 256 + tid] = (v < 32) ? accq[v] : acck[v - 32];
    }
    __syncthreads();
#pragma unroll
    for (int t4 = 0; t4 < 4; ++t4) {
      const int t2 = t4 * 256 + tid;
      const int s = t2 >> 7, c2 = t2 & 127;
      part[(size_t)blk * 8192 + (g * 8 + s) * 128 + c2] =
          red[s * 256 + c2] + red[s * 256 + 128 + c2];
    }
    __syncthreads();
  }
}

// ---------------- K2: reduce partials across blocks + bias ----------------
__global__ __launch_bounds__(256) void k_reduce(
    const float* __restrict__ part, int nblk,
    const float* __restrict__ bq, const float* __restrict__ bk,
    float* __restrict__ zq, float* __restrict__ zk) {
  const int j = blockIdx.x * 256 + threadIdx.x;  // 0..8191
  float s = 0.f;
  for (int b2 = 0; b2 < nblk; ++b2) s += part[(size_t)b2 * 8192 + j];
  const int v = j >> 7, c = j & 127, b = v & 31;
  if (v < 32) zq[b * FEATN + c] = s + bq[c];
  else        zk[b * FEATN + c] = s + fmaf(MM, bk[c], ONE_MM * bq[c]);
}

// ---------------- K3: normalize q,k; qq = sum q^2; l_pos ----------------
__device__ __forceinline__ float red128(float* red, int c, float v) {
  red[c] = v; __syncthreads();
#pragma unroll
  for (int s = 64; s >= 1; s >>= 1) {
    if (c < s) red[c] += red[c + s];
    __syncthreads();
  }
  const float r = red[0];
  __syncthreads();
  return r;
}

__global__ __launch_bounds__(128) void k_norm(
    const float* __restrict__ zq, const float* __restrict__ zk,
    float* __restrict__ q, float* __restrict__ kk,
    float* __restrict__ qq, float* __restrict__ lpos) {
  __shared__ float red[128];
  const int b = blockIdx.x, c = threadIdx.x;
  const float zqv = zq[b * FEATN + c], zkv = zk[b * FEATN + c];
  const float nq = sqrtf(red128(red, c, zqv * zqv));
  const float nk = sqrtf(red128(red, c, zkv * zkv));
  const float qv = zqv / fmaxf(nq, 1e-12f);
  const float kv = zkv / fmaxf(nk, 1e-12f);
  q[b * FEATN + c] = qv;
  kk[b * FEATN + c] = kv;
  const float qsq = red128(red, c, qv * qv);
  const float lp = red128(red, c, qv * kv);
  if (c == 0) { qq[b] = qsq; lpos[b] = lp; }
}

// ---------------- K4a: queue column squared norms ----------------
__global__ __launch_bounds__(256) void k_colnorm(const float* __restrict__ queue,
                                                 float* __restrict__ cn) {
  const int j = blockIdx.x * 256 + threadIdx.x;  // 0..511
  float s = 0.f;
  for (int c = 0; c < FEATN; ++c) { const float t = queue[c * KQ + j]; s = fmaf(t, t, s); }
  cn[j] = s;
}

// ---------------- K4b: queue-queue distances (batch independent) ----------------
__global__ __launch_bounds__(64) void k_dqq(const float* __restrict__ queue,
                                            const float* __restrict__ cn,
                                            float* __restrict__ Dqq) {
  const int i = blockIdx.x, t = threadIdx.x;
  float g[8];
#pragma unroll
  for (int u = 0; u < 8; ++u) g[u] = 0.f;
  for (int c = 0; c < FEATN; ++c) {
    const float qi = queue[c * KQ + i];  // uniform -> scalar
    const float* row = queue + c * KQ;
#pragma unroll
    for (int u = 0; u < 8; ++u) g[u] = fmaf(qi, row[u * 64 + t], g[u]);
  }
  const float cni = cn[i];
#pragma unroll
  for (int u = 0; u < 8; ++u) {
    const int j = u * 64 + t;
    const float d2 = cni + cn[j] - 2.f * g[u];
    Dqq[i * KQ + j] = sqrtf(fmaxf(d2, 0.f));
  }
}

// ---------------- K4c: q.queue dots and q-to-queue distances ----------------
__global__ __launch_bounds__(128) void k_dot(
    const float* __restrict__ q, const float* __restrict__ queue,
    const float* __restrict__ qq, const float* __restrict__ cn,
    float* __restrict__ dotq, float* __restrict__ d0) {
  const int b = blockIdx.x, t = threadIdx.x;
  float g[4];
#pragma unroll
  for (int u = 0; u < 4; ++u) g[u] = 0.f;
  for (int c = 0; c < FEATN; ++c) {
    const float qv = q[b * FEATN + c];  // uniform -> scalar
    const float* row = queue + c * KQ;
#pragma unroll
    for (int u = 0; u < 4; ++u) g[u] = fmaf(qv, row[u * 128 + t], g[u]);
  }
  const float qqb = qq[b];
#pragma unroll
  for (int u = 0; u < 4; ++u) {
    const int j = u * 128 + t;
    dotq[b * KQ + j] = g[u];
    const float d2 = qqb + cn[j] - 2.f * g[u];
    d0[b * KQ + j] = sqrtf(fmaxf(d2, 0.f));
  }
}

// ---------------- K5: per-row top-5-largest (stable-argsort tie rule) ----------------
// Reference keeps element j iff #{m: d_m > d_j} + #{m > j: d_m == d_j} < 5.
__device__ __forceinline__ bool beats(float v1, int i1, float v2, int i2) {
  return (v1 > v2) || ((v1 == v2) && (i1 > i2));
}

__global__ __launch_bounds__(256) void k_top5(
    const float* __restrict__ d0, const float* __restrict__ Dqq,
    int* __restrict__ ej, float* __restrict__ ew) {
  const int idx = blockIdx.x * 256 + threadIdx.x;
  if (idx >= BSZ * NN) return;
  const int b = idx / NN, i = idx % NN;
  const float NINF = -__builtin_inff();
  float tv0 = NINF, tv1 = NINF, tv2 = NINF, tv3 = NINF, tv4 = NINF;
  int ti0 = -1, ti1 = -1, ti2 = -1, ti3 = -1, ti4 = -1;
  const float* d0b = d0 + b * KQ;
  const float* Drow = (i > 0) ? (Dqq + (size_t)(i - 1) * KQ) : d0b;
  for (int j = 0; j < NN; ++j) {
    float vv;
    if (i == 0) vv = (j == 0) ? 0.f : d0b[j - 1];
    else if (j == 0) vv = d0b[i - 1];
    else vv = Drow[j - 1];
    if (beats(vv, j, tv4, ti4)) {
      tv4 = vv; ti4 = j;
      if (beats(tv4, ti4, tv3, ti3)) { float tf = tv3; tv3 = tv4; tv4 = tf; int tt = ti3; ti3 = ti4; ti4 = tt;
        if (beats(tv3, ti3, tv2, ti2)) { tf = tv2; tv2 = tv3; tv3 = tf; tt = ti2; ti2 = ti3; ti3 = tt;
          if (beats(tv2, ti2, tv1, ti1)) { tf = tv1; tv1 = tv2; tv2 = tf; tt = ti1; ti1 = ti2; ti2 = tt;
            if (beats(tv1, ti1, tv0, ti0)) { tf = tv0; tv0 = tv1; tv1 = tf; tt = ti0; ti0 = ti1; ti1 = tt; }
          }
        }
      }
    }
  }
  const int base = idx * 5;
  ej[base + 0] = (tv0 > 0.f) ? ti0 : -1; ew[base + 0] = tv0;
  ej[base + 1] = (tv1 > 0.f) ? ti1 : -1; ew[base + 1] = tv1;
  ej[base + 2] = (tv2 > 0.f) ? ti2 : -1; ew[base + 2] = tv2;
  ej[base + 3] = (tv3 > 0.f) ? ti3 : -1; ew[base + 3] = tv3;
  ej[base + 4] = (tv4 > 0.f) ? ti4 : -1; ew[base + 4] = tv4;
}

// ---------------- K6: SSSP from node 0 (Bellman-Ford to fixed point) ----------------
__global__ __launch_bounds__(256) void k_sssp(
    const int* __restrict__ ej, const float* __restrict__ ew,
    float* __restrict__ distout) {
  const int b = blockIdx.x, tid = threadIdx.x;
  __shared__ int dbits[NN];
  __shared__ int sej[NE];
  __shared__ float sew[NE];
  __shared__ int changed;
  for (int e = tid; e < NE; e += 256) { sej[e] = ej[b * NE + e]; sew[e] = ew[b * NE + e]; }
  for (int i = tid; i < NN; i += 256) dbits[i] = (i == 0) ? 0 : 0x7f800000;
  __syncthreads();
  for (int it = 0; it < 600; ++it) {
    if (tid == 0) changed = 0;
    __syncthreads();
    int any = 0;
    for (int e = tid; e < NE; e += 256) {
      const int dst = sej[e];
      if (dst < 0) continue;
      const int sb = dbits[e / 5];
      if (sb == 0x7f800000) continue;
      const float cand = __int_as_float(sb) + sew[e];
      const int cb = __float_as_int(cand);  // nonneg floats: int order == float order
      if (cb < dbits[dst]) { atomicMin(&dbits[dst], cb); any = 1; }
    }
    if (any) atomicOr(&changed, 1);
    __syncthreads();
    if (changed == 0) break;
    __syncthreads();  // protect 'changed' against next-iter reset
  }
  for (int i = tid; i < KQ; i += 256) distout[b * KQ + i] = __int_as_float(dbits[i + 1]);
}

// ---------------- K7: global max, weights, logits, labels ----------------
__global__ __launch_bounds__(512) void k_final(
    const float* __restrict__ dist, const float* __restrict__ dotq,
    const float* __restrict__ lpos, float* __restrict__ out) {
  __shared__ float red[512];
  const int tid = threadIdx.x;
  float mx = 0.f;
  for (int idx = tid; idx < BSZ * KQ; idx += 512) {
    const float d = dist[idx];
    if (d != __builtin_inff()) mx = fmaxf(mx, d);
  }
  red[tid] = mx; __syncthreads();
#pragma unroll
  for (int s = 256; s >= 1; s >>= 1) {
    if (tid < s) red[tid] = fmaxf(red[tid], red[tid + s]);
    __syncthreads();
  }
  const float MX = red[0];
  for (int idx = tid; idx < BSZ * KQ; idx += 512) {
    float d = dist[idx];
    if (d == __builtin_inff()) d = MX + 1.f;
    const float w = 1.f / (1.f + d);
    const int b = idx >> 9, j = idx & 511;
    out[b * NN + 1 + j] = dotq[idx] * w / TT;
  }
  if (tid < BSZ) {
    out[tid * NN] = lpos[tid] / TT;   // l_pos column
    out[BSZ * NN + tid] = 0.f;        // labels: int32 zeros == float 0.0f bits
  }
}

// ---------------- launcher ----------------
extern "C" void kernel_launch(void* const* d_in, const int* in_sizes, int n_in,
                              void* d_out, int out_size, void* d_ws, size_t ws_size,
                              hipStream_t stream) {
  const float* Xq    = (const float*)d_in[0];
  const float* Xk    = (const float*)d_in[1];
  const float* Wq    = (const float*)d_in[2];
  const float* bq    = (const float*)d_in[3];
  const float* Wk    = (const float*)d_in[4];
  const float* bk    = (const float*)d_in[5];
  const float* queue = (const float*)d_in[6];
  float* out = (float*)d_out;
  float* ws = (float*)d_ws;

  // fixed region size (floats) placed after the variable partials region
  const size_t fixed_elems =
      4096 * 4 + 32 + 32 + 512 + 262144 + 16384 * 3 + 82080 * 2;
  // pick split-K block count so everything fits in ws
  int nblk = 512;
  while (nblk > 64 && ((size_t)nblk * 8192 + fixed_elems) * 4 > ws_size) nblk >>= 1;
  const int chunk = DIN / nblk;  // 98/196/392/784, all even

  float* part = ws;
  float* base = ws + (size_t)nblk * 8192;
  float* zq   = base;          // 4096
  float* zk   = zq + 4096;     // 4096
  float* q    = zk + 4096;     // 4096
  float* kk   = q + 4096;      // 4096
  float* qq   = kk + 4096;     // 32
  float* lpos = qq + 32;       // 32
  float* cn   = lpos + 32;     // 512
  float* Dqq  = cn + 512;      // 262144
  float* dotq = Dqq + 262144;  // 16384
  float* d0   = dotq + 16384;  // 16384
  float* dist = d0 + 16384;    // 16384
  int*   ej   = (int*)(dist + 16384);  // 82080 ints
  float* ew   = (float*)(ej + 82080);  // 82080 floats

  hipLaunchKernelGGL(k_dualgemm, dim3(nblk), dim3(256), 0, stream, Xq, Xk, Wq, Wk, part, chunk);
  hipLaunchKernelGGL(k_reduce,   dim3(32),   dim3(256), 0, stream, part, nblk, bq, bk, zq, zk);
  hipLaunchKernelGGL(k_norm,     dim3(32),   dim3(128), 0, stream, zq, zk, q, kk, qq, lpos);
  hipLaunchKernelGGL(k_colnorm,  dim3(2),    dim3(256), 0, stream, queue, cn);
  hipLaunchKernelGGL(k_dqq,      dim3(512),  dim3(64),  0, stream, queue, cn, Dqq);
  hipLaunchKernelGGL(k_dot,      dim3(32),   dim3(128), 0, stream, q, queue, qq, cn, dotq, d0);
  hipLaunchKernelGGL(k_top5,     dim3((BSZ * NN + 255) / 256), dim3(256), 0, stream, d0, Dqq, ej, ew);
  hipLaunchKernelGGL(k_sssp,     dim3(BSZ),  dim3(256), 0, stream, ej, ew, dist);
  hipLaunchKernelGGL(k_final,    dim3(1),    dim3(512), 0, stream, dist, dotq, lpos, out);
}

// Round 3
// 368.157 us; speedup vs baseline: 1.2877x; 1.2877x over previous
//
#include <hip/hip_runtime.h>
#include <math.h>

#define DIN 50176
#define BSZ 32
#define FEATN 128
#define KQ 512
#define NN 513      // KQ + 1
#define NE (NN * 5) // 2565 edges per batch
#define MM 0.999f
#define ONE_MM 0.001f
#define TT 0.07f

// ---------------- K1: fused dual GEMM, split-K, deterministic partials ----------------
// z_q[b][c] = sum_k Xq[b][k] * Wq[k][c]
// z_k[b][c] = sum_k Xk[b][k] * (M*Wk[k][c] + (1-M)*Wq[k][c])
// grid: nblk blocks x 256 threads; thread = (c = tid&127, r = tid>>7 in {0,1})
// Each block covers `chunk` consecutive k. X values are wave-uniform -> scalar loads.
__global__ __launch_bounds__(256) void k_dualgemm(
    const float* __restrict__ Xq, const float* __restrict__ Xk,
    const float* __restrict__ Wq, const float* __restrict__ Wk,
    float* __restrict__ part, int chunk) {
  const int tid = threadIdx.x;
  const int c = tid & 127;
  const int r = tid >> 7;       // wave-uniform (128-thread groups = 2 waves)
  const int blk = blockIdx.x;
  float accq[32], acck[32];
#pragma unroll
  for (int b = 0; b < 32; ++b) { accq[b] = 0.f; acck[b] = 0.f; }
  const int k0 = blk * chunk + r;
  const int iters = chunk >> 1;
  for (int i = 0; i < iters; ++i) {
    const int ku = __builtin_amdgcn_readfirstlane(k0 + 2 * i);
    const float wq = Wq[ku * FEATN + c];
    const float wk = Wk[ku * FEATN + c];
    const float w2 = fmaf(MM, wk, ONE_MM * wq);
    const float* xq = Xq + ku;
    const float* xk = Xk + ku;
#pragma unroll
    for (int b = 0; b < 32; ++b) {
      accq[b] = fmaf(wq, xq[b * DIN], accq[b]);   // uniform addr -> s_load
      acck[b] = fmaf(w2, xk[b * DIN], acck[b]);
    }
  }
  // Reduce over r (2 copies) via LDS, write 8192 partials per block.
  __shared__ float red[8 * 256];
#pragma unroll
  for (int g = 0; g < 8; ++g) {
#pragma unroll
    for (int s = 0; s < 8; ++s) {
      const int v = g * 8 + s;
      red[s * 256 + tid] = (v < 32) ? accq[v] : acck[v - 32];
    }
    __syncthreads();
#pragma unroll
    for (int t4 = 0; t4 < 4; ++t4) {
      const int t2 = t4 * 256 + tid;
      const int s = t2 >> 7, c2 = t2 & 127;
      part[(size_t)blk * 8192 + (g * 8 + s) * 128 + c2] =
          red[s * 256 + c2] + red[s * 256 + 128 + c2];
    }
    __syncthreads();
  }
}

// ---------------- K2: reduce partials across blocks + bias ----------------
__global__ __launch_bounds__(256) void k_reduce(
    const float* __restrict__ part, int nblk,
    const float* __restrict__ bq, const float* __restrict__ bk,
    float* __restrict__ zq, float* __restrict__ zk) {
  const int j = blockIdx.x * 256 + threadIdx.x;  // 0..8191
  float s = 0.f;
  for (int b2 = 0; b2 < nblk; ++b2) s += part[(size_t)b2 * 8192 + j];
  const int v = j >> 7, c = j & 127, b = v & 31;
  if (v < 32) zq[b * FEATN + c] = s + bq[c];
  else        zk[b * FEATN + c] = s + fmaf(MM, bk[c], ONE_MM * bq[c]);
}

// ---------------- K3: normalize q,k; qq = sum q^2; l_pos ----------------
__device__ __forceinline__ float red128(float* red, int c, float v) {
  red[c] = v; __syncthreads();
#pragma unroll
  for (int s = 64; s >= 1; s >>= 1) {
    if (c < s) red[c] += red[c + s];
    __syncthreads();
  }
  const float r = red[0];
  __syncthreads();
  return r;
}

__global__ __launch_bounds__(128) void k_norm(
    const float* __restrict__ zq, const float* __restrict__ zk,
    float* __restrict__ q, float* __restrict__ kk,
    float* __restrict__ qq, float* __restrict__ lpos) {
  __shared__ float red[128];
  const int b = blockIdx.x, c = threadIdx.x;
  const float zqv = zq[b * FEATN + c], zkv = zk[b * FEATN + c];
  const float nq = sqrtf(red128(red, c, zqv * zqv));
  const float nk = sqrtf(red128(red, c, zkv * zkv));
  const float qv = zqv / fmaxf(nq, 1e-12f);
  const float kv = zkv / fmaxf(nk, 1e-12f);
  q[b * FEATN + c] = qv;
  kk[b * FEATN + c] = kv;
  const float qsq = red128(red, c, qv * qv);
  const float lp = red128(red, c, qv * kv);
  if (c == 0) { qq[b] = qsq; lpos[b] = lp; }
}

// ---------------- K4a: queue column squared norms ----------------
__global__ __launch_bounds__(256) void k_colnorm(const float* __restrict__ queue,
                                                 float* __restrict__ cn) {
  const int j = blockIdx.x * 256 + threadIdx.x;  // 0..511
  float s = 0.f;
  for (int c = 0; c < FEATN; ++c) { const float t = queue[c * KQ + j]; s = fmaf(t, t, s); }
  cn[j] = s;
}

// ---------------- K4b: queue-queue distances (batch independent) ----------------
__global__ __launch_bounds__(64) void k_dqq(const float* __restrict__ queue,
                                            const float* __restrict__ cn,
                                            float* __restrict__ Dqq) {
  const int i = blockIdx.x, t = threadIdx.x;
  float g[8];
#pragma unroll
  for (int u = 0; u < 8; ++u) g[u] = 0.f;
  for (int c = 0; c < FEATN; ++c) {
    const float qi = queue[c * KQ + i];  // uniform -> scalar
    const float* row = queue + c * KQ;
#pragma unroll
    for (int u = 0; u < 8; ++u) g[u] = fmaf(qi, row[u * 64 + t], g[u]);
  }
  const float cni = cn[i];
#pragma unroll
  for (int u = 0; u < 8; ++u) {
    const int j = u * 64 + t;
    const float d2 = cni + cn[j] - 2.f * g[u];
    Dqq[i * KQ + j] = sqrtf(fmaxf(d2, 0.f));
  }
}

// ---------------- K4c: q.queue dots and q-to-queue distances ----------------
__global__ __launch_bounds__(128) void k_dot(
    const float* __restrict__ q, const float* __restrict__ queue,
    const float* __restrict__ qq, const float* __restrict__ cn,
    float* __restrict__ dotq, float* __restrict__ d0) {
  const int b = blockIdx.x, t = threadIdx.x;
  float g[4];
#pragma unroll
  for (int u = 0; u < 4; ++u) g[u] = 0.f;
  for (int c = 0; c < FEATN; ++c) {
    const float qv = q[b * FEATN + c];  // uniform -> scalar
    const float* row = queue + c * KQ;
#pragma unroll
    for (int u = 0; u < 4; ++u) g[u] = fmaf(qv, row[u * 128 + t], g[u]);
  }
  const float qqb = qq[b];
#pragma unroll
  for (int u = 0; u < 4; ++u) {
    const int j = u * 128 + t;
    dotq[b * KQ + j] = g[u];
    const float d2 = qqb + cn[j] - 2.f * g[u];
    d0[b * KQ + j] = sqrtf(fmaxf(d2, 0.f));
  }
}

// ---------------- K5: per-row top-5-largest, one WAVE per row ----------------
// Reference rule: keep element j iff #{m: d_m > d_j} + #{m > j: d_m == d_j} < 5.
// Equivalent: top-5 under key = (float_bits(d) << 32) | j  (all d >= 0, so
// float bit order == value order; larger index wins ties).
__global__ __launch_bounds__(256) void k_top5w(
    const float* __restrict__ d0, const float* __restrict__ Dqq,
    int* __restrict__ ej, float* __restrict__ ew) {
  const int wid = (blockIdx.x * 256 + threadIdx.x) >> 6;  // row id 0..16415
  const int lane = threadIdx.x & 63;
  if (wid >= BSZ * NN) return;
  const int b = wid / NN, i = wid % NN;
  const float* d0b = d0 + b * KQ;
  const float* Drow = Dqq + (size_t)(i > 0 ? i - 1 : 0) * KQ;

  unsigned long long key[9];
#pragma unroll
  for (int u = 0; u < 9; ++u) {
    const int j = lane + 64 * u;
    const bool valid = (j < NN);
    float vv = 0.f;
    if (valid) {
      if (i == 0) vv = (j == 0) ? 0.f : d0b[j - 1];
      else if (j == 0) vv = d0b[i - 1];
      else vv = Drow[j - 1];
    }
    key[u] = valid
        ? (((unsigned long long)__float_as_uint(vv) << 32) | (unsigned)j)
        : 0ULL;  // sentinel: value 0 / index 0 — can only occupy slots that
                 // would hold d<=0 entries, which all become ej=-1 anyway
  }

  unsigned long long r0, r1, r2, r3, r4;
#pragma unroll
  for (int r = 0; r < 5; ++r) {
    unsigned long long m = key[0];
#pragma unroll
    for (int u = 1; u < 9; ++u) m = (key[u] > m) ? key[u] : m;
#pragma unroll
    for (int s = 1; s < 64; s <<= 1) {
      const unsigned long long o = __shfl_xor(m, s, 64);
      m = (o > m) ? o : m;
    }
    if (r == 0) r0 = m; else if (r == 1) r1 = m; else if (r == 2) r2 = m;
    else if (r == 3) r3 = m; else r4 = m;
#pragma unroll
    for (int u = 0; u < 9; ++u) if (key[u] == m) key[u] = 0ULL;
  }

  if (lane < 5) {
    unsigned long long m = r0;
    if (lane == 1) m = r1;
    else if (lane == 2) m = r2;
    else if (lane == 3) m = r3;
    else if (lane == 4) m = r4;
    const float v = __uint_as_float((unsigned)(m >> 32));
    const int idx = (int)(unsigned)(m & 0xffffffffu);
    const int base = wid * 5 + lane;
    ej[base] = (v > 0.f) ? idx : -1;
    ew[base] = v;
  }
}

// ---------------- K6: SSSP from node 0 (Bellman-Ford to fixed point) ----------------
__global__ __launch_bounds__(256) void k_sssp(
    const int* __restrict__ ej, const float* __restrict__ ew,
    float* __restrict__ distout) {
  const int b = blockIdx.x, tid = threadIdx.x;
  __shared__ int dbits[NN];
  __shared__ int sej[NE];
  __shared__ float sew[NE];
  __shared__ int changed;
  for (int e = tid; e < NE; e += 256) { sej[e] = ej[b * NE + e]; sew[e] = ew[b * NE + e]; }
  for (int i = tid; i < NN; i += 256) dbits[i] = (i == 0) ? 0 : 0x7f800000;
  __syncthreads();
  for (int it = 0; it < 600; ++it) {
    if (tid == 0) changed = 0;
    __syncthreads();
    int any = 0;
    for (int e = tid; e < NE; e += 256) {
      const int dst = sej[e];
      if (dst < 0) continue;
      const int sb = dbits[e / 5];
      if (sb == 0x7f800000) continue;
      const float cand = __int_as_float(sb) + sew[e];
      const int cb = __float_as_int(cand);  // nonneg floats: int order == float order
      if (cb < dbits[dst]) { atomicMin(&dbits[dst], cb); any = 1; }
    }
    if (any) atomicOr(&changed, 1);
    __syncthreads();
    if (changed == 0) break;
    __syncthreads();  // protect 'changed' against next-iter reset
  }
  for (int i = tid; i < KQ; i += 256) distout[b * KQ + i] = __int_as_float(dbits[i + 1]);
}

// ---------------- K7: global max, weights, logits, labels ----------------
__global__ __launch_bounds__(512) void k_final(
    const float* __restrict__ dist, const float* __restrict__ dotq,
    const float* __restrict__ lpos, float* __restrict__ out) {
  __shared__ float red[512];
  const int tid = threadIdx.x;
  float mx = 0.f;
  for (int idx = tid; idx < BSZ * KQ; idx += 512) {
    const float d = dist[idx];
    if (d != __builtin_inff()) mx = fmaxf(mx, d);
  }
  red[tid] = mx; __syncthreads();
#pragma unroll
  for (int s = 256; s >= 1; s >>= 1) {
    if (tid < s) red[tid] = fmaxf(red[tid], red[tid + s]);
    __syncthreads();
  }
  const float MX = red[0];
  for (int idx = tid; idx < BSZ * KQ; idx += 512) {
    float d = dist[idx];
    if (d == __builtin_inff()) d = MX + 1.f;
    const float w = 1.f / (1.f + d);
    const int b = idx >> 9, j = idx & 511;
    out[b * NN + 1 + j] = dotq[idx] * w / TT;
  }
  if (tid < BSZ) {
    out[tid * NN] = lpos[tid] / TT;   // l_pos column
    out[BSZ * NN + tid] = 0.f;        // labels: int32 zeros == float 0.0f bits
  }
}

// ---------------- launcher ----------------
extern "C" void kernel_launch(void* const* d_in, const int* in_sizes, int n_in,
                              void* d_out, int out_size, void* d_ws, size_t ws_size,
                              hipStream_t stream) {
  const float* Xq    = (const float*)d_in[0];
  const float* Xk    = (const float*)d_in[1];
  const float* Wq    = (const float*)d_in[2];
  const float* bq    = (const float*)d_in[3];
  const float* Wk    = (const float*)d_in[4];
  const float* bk    = (const float*)d_in[5];
  const float* queue = (const float*)d_in[6];
  float* out = (float*)d_out;
  float* ws = (float*)d_ws;

  // fixed region size (floats) placed after the variable partials region
  const size_t fixed_elems =
      4096 * 4 + 32 + 32 + 512 + 262144 + 16384 * 3 + 82080 * 2;
  // pick split-K block count so everything fits in ws
  int nblk = 512;
  while (nblk > 64 && ((size_t)nblk * 8192 + fixed_elems) * 4 > ws_size) nblk >>= 1;
  const int chunk = DIN / nblk;  // 98/196/392/784, all even

  float* part = ws;
  float* base = ws + (size_t)nblk * 8192;
  float* zq   = base;          // 4096
  float* zk   = zq + 4096;     // 4096
  float* q    = zk + 4096;     // 4096
  float* kk   = q + 4096;      // 4096
  float* qq   = kk + 4096;     // 32
  float* lpos = qq + 32;       // 32
  float* cn   = lpos + 32;     // 512
  float* Dqq  = cn + 512;      // 262144
  float* dotq = Dqq + 262144;  // 16384
  float* d0   = dotq + 16384;  // 16384
  float* dist = d0 + 16384;    // 16384
  int*   ej   = (int*)(dist + 16384);  // 82080 ints
  float* ew   = (float*)(ej + 82080);  // 82080 floats

  hipLaunchKernelGGL(k_dualgemm, dim3(nblk), dim3(256), 0, stream, Xq, Xk, Wq, Wk, part, chunk);
  hipLaunchKernelGGL(k_reduce,   dim3(32),   dim3(256), 0, stream, part, nblk, bq, bk, zq, zk);
  hipLaunchKernelGGL(k_norm,     dim3(32),   dim3(128), 0, stream, zq, zk, q, kk, qq, lpos);
  hipLaunchKernelGGL(k_colnorm,  dim3(2),    dim3(256), 0, stream, queue, cn);
  hipLaunchKernelGGL(k_dqq,      dim3(512),  dim3(64),  0, stream, queue, cn, Dqq);
  hipLaunchKernelGGL(k_dot,      dim3(32),   dim3(128), 0, stream, q, queue, qq, cn, dotq, d0);
  hipLaunchKernelGGL(k_top5w,    dim3((BSZ * NN * 64 + 255) / 256), dim3(256), 0, stream, d0, Dqq, ej, ew);
  hipLaunchKernelGGL(k_sssp,     dim3(BSZ),  dim3(256), 0, stream, ej, ew, dist);
  hipLaunchKernelGGL(k_final,    dim3(1),    dim3(512), 0, stream, dist, dotq, lpos, out);
}

// Round 4
// 261.710 us; speedup vs baseline: 1.8114x; 1.4067x over previous
//
#include <hip/hip_runtime.h>
#include <math.h>

#define DIN 50176
#define BSZ 32
#define FEATN 128
#define KQ 512
#define NN 513      // KQ + 1
#define NE (NN * 5) // 2565 edges per batch
#define MM 0.999f
#define ONE_MM 0.001f
#define TT 0.07f
#define RCHUNKS 16  // second-level reduction fan-in

// ---------------- K1: fused dual GEMM, split-K, deterministic partials ----------------
// z_q[b][c] = sum_k Xq[b][k] * Wq[k][c]
// z_k[b][c] = sum_k Xk[b][k] * (M*Wk[k][c] + (1-M)*Wq[k][c])
// grid: nblk blocks x 256 threads; thread = (c = tid&127, r = tid>>7 in {0,1})
// Each block covers `chunk` consecutive k. X values are wave-uniform -> scalar loads.
__global__ __launch_bounds__(256) void k_dualgemm(
    const float* __restrict__ Xq, const float* __restrict__ Xk,
    const float* __restrict__ Wq, const float* __restrict__ Wk,
    float* __restrict__ part, int chunk) {
  const int tid = threadIdx.x;
  const int c = tid & 127;
  const int r = tid >> 7;       // wave-uniform (128-thread groups = 2 waves)
  const int blk = blockIdx.x;
  float accq[32], acck[32];
#pragma unroll
  for (int b = 0; b < 32; ++b) { accq[b] = 0.f; acck[b] = 0.f; }
  const int k0 = blk * chunk + r;
  const int iters = chunk >> 1;
  for (int i = 0; i < iters; ++i) {
    const int ku = __builtin_amdgcn_readfirstlane(k0 + 2 * i);
    const float wq = Wq[ku * FEATN + c];
    const float wk = Wk[ku * FEATN + c];
    const float w2 = fmaf(MM, wk, ONE_MM * wq);
    const float* xq = Xq + ku;
    const float* xk = Xk + ku;
#pragma unroll
    for (int b = 0; b < 32; ++b) {
      accq[b] = fmaf(wq, xq[b * DIN], accq[b]);   // uniform addr -> s_load
      acck[b] = fmaf(w2, xk[b * DIN], acck[b]);
    }
  }
  // Reduce over r (2 copies) via LDS, write 8192 partials per block.
  __shared__ float red[8 * 256];
#pragma unroll
  for (int g = 0; g < 8; ++g) {
#pragma unroll
    for (int s = 0; s < 8; ++s) {
      const int v = g * 8 + s;
      red[s * 256 + tid] = (v < 32) ? accq[v] : acck[v - 32];
    }
    __syncthreads();
#pragma unroll
    for (int t4 = 0; t4 < 4; ++t4) {
      const int t2 = t4 * 256 + tid;
      const int s = t2 >> 7, c2 = t2 & 127;
      part[(size_t)blk * 8192 + (g * 8 + s) * 128 + c2] =
          red[s * 256 + c2] + red[s * 256 + 128 + c2];
    }
    __syncthreads();
  }
}

// ---------------- K2a: stage-A partial reduction (16x parallel over k-chunks) ----------------
// grid = RCHUNKS * 32 blocks; block (jb, ch) sums nblk/RCHUNKS partials for 256 j's.
__global__ __launch_bounds__(256) void k_reduceA(
    const float* __restrict__ part, float* __restrict__ part2, int per_chunk) {
  const int j = (blockIdx.x & 31) * 256 + threadIdx.x;  // 0..8191
  const int ch = blockIdx.x >> 5;                       // 0..RCHUNKS-1
  const float* p = part + (size_t)ch * per_chunk * 8192 + j;
  float s = 0.f;
  for (int b2 = 0; b2 < per_chunk; ++b2) s += p[(size_t)b2 * 8192];
  part2[(size_t)ch * 8192 + j] = s;
}

// ---------------- K2b: stage-B reduction + bias ----------------
__global__ __launch_bounds__(256) void k_reduceB(
    const float* __restrict__ part2,
    const float* __restrict__ bq, const float* __restrict__ bk,
    float* __restrict__ zq, float* __restrict__ zk) {
  const int j = blockIdx.x * 256 + threadIdx.x;  // 0..8191
  float s = 0.f;
#pragma unroll
  for (int ch = 0; ch < RCHUNKS; ++ch) s += part2[(size_t)ch * 8192 + j];
  const int v = j >> 7, c = j & 127, b = v & 31;
  if (v < 32) zq[b * FEATN + c] = s + bq[c];
  else        zk[b * FEATN + c] = s + fmaf(MM, bk[c], ONE_MM * bq[c]);
}

// ---------------- K3: normalize q,k; qq = sum q^2; l_pos ----------------
__device__ __forceinline__ float red128(float* red, int c, float v) {
  red[c] = v; __syncthreads();
#pragma unroll
  for (int s = 64; s >= 1; s >>= 1) {
    if (c < s) red[c] += red[c + s];
    __syncthreads();
  }
  const float r = red[0];
  __syncthreads();
  return r;
}

__global__ __launch_bounds__(128) void k_norm(
    const float* __restrict__ zq, const float* __restrict__ zk,
    float* __restrict__ q, float* __restrict__ kk,
    float* __restrict__ qq, float* __restrict__ lpos) {
  __shared__ float red[128];
  const int b = blockIdx.x, c = threadIdx.x;
  const float zqv = zq[b * FEATN + c], zkv = zk[b * FEATN + c];
  const float nq = sqrtf(red128(red, c, zqv * zqv));
  const float nk = sqrtf(red128(red, c, zkv * zkv));
  const float qv = zqv / fmaxf(nq, 1e-12f);
  const float kv = zkv / fmaxf(nk, 1e-12f);
  q[b * FEATN + c] = qv;
  kk[b * FEATN + c] = kv;
  const float qsq = red128(red, c, qv * qv);
  const float lp = red128(red, c, qv * kv);
  if (c == 0) { qq[b] = qsq; lpos[b] = lp; }
}

// ---------------- K4a: queue column squared norms ----------------
__global__ __launch_bounds__(256) void k_colnorm(const float* __restrict__ queue,
                                                 float* __restrict__ cn) {
  const int j = blockIdx.x * 256 + threadIdx.x;  // 0..511
  float s = 0.f;
  for (int c = 0; c < FEATN; ++c) { const float t = queue[c * KQ + j]; s = fmaf(t, t, s); }
  cn[j] = s;
}

// ---------------- K4b: queue-queue distances (batch independent) ----------------
__global__ __launch_bounds__(64) void k_dqq(const float* __restrict__ queue,
                                            const float* __restrict__ cn,
                                            float* __restrict__ Dqq) {
  const int i = blockIdx.x, t = threadIdx.x;
  float g[8];
#pragma unroll
  for (int u = 0; u < 8; ++u) g[u] = 0.f;
  for (int c = 0; c < FEATN; ++c) {
    const float qi = queue[c * KQ + i];  // uniform -> scalar
    const float* row = queue + c * KQ;
#pragma unroll
    for (int u = 0; u < 8; ++u) g[u] = fmaf(qi, row[u * 64 + t], g[u]);
  }
  const float cni = cn[i];
#pragma unroll
  for (int u = 0; u < 8; ++u) {
    const int j = u * 64 + t;
    const float d2 = cni + cn[j] - 2.f * g[u];
    Dqq[i * KQ + j] = sqrtf(fmaxf(d2, 0.f));
  }
}

// ---------------- K4c: q.queue dots and q-to-queue distances ----------------
__global__ __launch_bounds__(128) void k_dot(
    const float* __restrict__ q, const float* __restrict__ queue,
    const float* __restrict__ qq, const float* __restrict__ cn,
    float* __restrict__ dotq, float* __restrict__ d0) {
  const int b = blockIdx.x, t = threadIdx.x;
  float g[4];
#pragma unroll
  for (int u = 0; u < 4; ++u) g[u] = 0.f;
  for (int c = 0; c < FEATN; ++c) {
    const float qv = q[b * FEATN + c];  // uniform -> scalar
    const float* row = queue + c * KQ;
#pragma unroll
    for (int u = 0; u < 4; ++u) g[u] = fmaf(qv, row[u * 128 + t], g[u]);
  }
  const float qqb = qq[b];
#pragma unroll
  for (int u = 0; u < 4; ++u) {
    const int j = u * 128 + t;
    dotq[b * KQ + j] = g[u];
    const float d2 = qqb + cn[j] - 2.f * g[u];
    d0[b * KQ + j] = sqrtf(fmaxf(d2, 0.f));
  }
}

// ---------------- K5: per-row top-5-largest, one WAVE per row ----------------
// Reference rule: keep element j iff #{m: d_m > d_j} + #{m > j: d_m == d_j} < 5.
// Equivalent: top-5 under key = (float_bits(d) << 32) | j  (all d >= 0, so
// float bit order == value order; larger index wins ties).
__global__ __launch_bounds__(256) void k_top5w(
    const float* __restrict__ d0, const float* __restrict__ Dqq,
    int* __restrict__ ej, float* __restrict__ ew) {
  const int wid = (blockIdx.x * 256 + threadIdx.x) >> 6;  // row id 0..16415
  const int lane = threadIdx.x & 63;
  if (wid >= BSZ * NN) return;
  const int b = wid / NN, i = wid % NN;
  const float* d0b = d0 + b * KQ;
  const float* Drow = Dqq + (size_t)(i > 0 ? i - 1 : 0) * KQ;

  unsigned long long key[9];
#pragma unroll
  for (int u = 0; u < 9; ++u) {
    const int j = lane + 64 * u;
    const bool valid = (j < NN);
    float vv = 0.f;
    if (valid) {
      if (i == 0) vv = (j == 0) ? 0.f : d0b[j - 1];
      else if (j == 0) vv = d0b[i - 1];
      else vv = Drow[j - 1];
    }
    key[u] = valid
        ? (((unsigned long long)__float_as_uint(vv) << 32) | (unsigned)j)
        : 0ULL;  // sentinel: value 0 / index 0 — can only occupy slots that
                 // would hold d<=0 entries, which all become ej=-1 anyway
  }

  unsigned long long r0, r1, r2, r3, r4;
#pragma unroll
  for (int r = 0; r < 5; ++r) {
    unsigned long long m = key[0];
#pragma unroll
    for (int u = 1; u < 9; ++u) m = (key[u] > m) ? key[u] : m;
#pragma unroll
    for (int s = 1; s < 64; s <<= 1) {
      const unsigned long long o = __shfl_xor(m, s, 64);
      m = (o > m) ? o : m;
    }
    if (r == 0) r0 = m; else if (r == 1) r1 = m; else if (r == 2) r2 = m;
    else if (r == 3) r3 = m; else r4 = m;
#pragma unroll
    for (int u = 0; u < 9; ++u) if (key[u] == m) key[u] = 0ULL;
  }

  if (lane < 5) {
    unsigned long long m = r0;
    if (lane == 1) m = r1;
    else if (lane == 2) m = r2;
    else if (lane == 3) m = r3;
    else if (lane == 4) m = r4;
    const float v = __uint_as_float((unsigned)(m >> 32));
    const int idx = (int)(unsigned)(m & 0xffffffffu);
    const int base = wid * 5 + lane;
    ej[base] = (v > 0.f) ? idx : -1;
    ew[base] = v;
  }
}

// ---------------- K6: SSSP from node 0 (Bellman-Ford to fixed point) ----------------
__global__ __launch_bounds__(256) void k_sssp(
    const int* __restrict__ ej, const float* __restrict__ ew,
    float* __restrict__ distout) {
  const int b = blockIdx.x, tid = threadIdx.x;
  __shared__ int dbits[NN];
  __shared__ int sej[NE];
  __shared__ float sew[NE];
  __shared__ int changed;
  for (int e = tid; e < NE; e += 256) { sej[e] = ej[b * NE + e]; sew[e] = ew[b * NE + e]; }
  for (int i = tid; i < NN; i += 256) dbits[i] = (i == 0) ? 0 : 0x7f800000;
  __syncthreads();
  for (int it = 0; it < 600; ++it) {
    if (tid == 0) changed = 0;
    __syncthreads();
    int any = 0;
    for (int e = tid; e < NE; e += 256) {
      const int dst = sej[e];
      if (dst < 0) continue;
      const int sb = dbits[e / 5];
      if (sb == 0x7f800000) continue;
      const float cand = __int_as_float(sb) + sew[e];
      const int cb = __float_as_int(cand);  // nonneg floats: int order == float order
      if (cb < dbits[dst]) { atomicMin(&dbits[dst], cb); any = 1; }
    }
    if (any) atomicOr(&changed, 1);
    __syncthreads();
    if (changed == 0) break;
    __syncthreads();  // protect 'changed' against next-iter reset
  }
  for (int i = tid; i < KQ; i += 256) distout[b * KQ + i] = __int_as_float(dbits[i + 1]);
}

// ---------------- K7: global max, weights, logits, labels ----------------
__global__ __launch_bounds__(512) void k_final(
    const float* __restrict__ dist, const float* __restrict__ dotq,
    const float* __restrict__ lpos, float* __restrict__ out) {
  __shared__ float red[512];
  const int tid = threadIdx.x;
  float mx = 0.f;
  for (int idx = tid; idx < BSZ * KQ; idx += 512) {
    const float d = dist[idx];
    if (d != __builtin_inff()) mx = fmaxf(mx, d);
  }
  red[tid] = mx; __syncthreads();
#pragma unroll
  for (int s = 256; s >= 1; s >>= 1) {
    if (tid < s) red[tid] = fmaxf(red[tid], red[tid + s]);
    __syncthreads();
  }
  const float MX = red[0];
  for (int idx = tid; idx < BSZ * KQ; idx += 512) {
    float d = dist[idx];
    if (d == __builtin_inff()) d = MX + 1.f;
    const float w = 1.f / (1.f + d);
    const int b = idx >> 9, j = idx & 511;
    out[b * NN + 1 + j] = dotq[idx] * w / TT;
  }
  if (tid < BSZ) {
    out[tid * NN] = lpos[tid] / TT;   // l_pos column
    out[BSZ * NN + tid] = 0.f;        // labels: int32 zeros == float 0.0f bits
  }
}

// ---------------- launcher ----------------
extern "C" void kernel_launch(void* const* d_in, const int* in_sizes, int n_in,
                              void* d_out, int out_size, void* d_ws, size_t ws_size,
                              hipStream_t stream) {
  const float* Xq    = (const float*)d_in[0];
  const float* Xk    = (const float*)d_in[1];
  const float* Wq    = (const float*)d_in[2];
  const float* bq    = (const float*)d_in[3];
  const float* Wk    = (const float*)d_in[4];
  const float* bk    = (const float*)d_in[5];
  const float* queue = (const float*)d_in[6];
  float* out = (float*)d_out;
  float* ws = (float*)d_ws;

  // fixed region size (floats) placed after the variable partials region
  const size_t fixed_elems =
      RCHUNKS * 8192 + 4096 * 4 + 32 + 32 + 512 + 262144 + 16384 * 3 + 82080 * 2;
  // pick split-K block count so everything fits in ws
  int nblk = 512;
  while (nblk > 64 && ((size_t)nblk * 8192 + fixed_elems) * 4 > ws_size) nblk >>= 1;
  const int chunk = DIN / nblk;  // 98/196/392/784, all even
  const int per_chunk = nblk / RCHUNKS;

  float* part = ws;
  float* base = ws + (size_t)nblk * 8192;
  float* part2 = base;               // RCHUNKS * 8192
  float* zq   = part2 + RCHUNKS * 8192;  // 4096
  float* zk   = zq + 4096;     // 4096
  float* q    = zk + 4096;     // 4096
  float* kk   = q + 4096;      // 4096
  float* qq   = kk + 4096;     // 32
  float* lpos = qq + 32;       // 32
  float* cn   = lpos + 32;     // 512
  float* Dqq  = cn + 512;      // 262144
  float* dotq = Dqq + 262144;  // 16384
  float* d0   = dotq + 16384;  // 16384
  float* dist = d0 + 16384;    // 16384
  int*   ej   = (int*)(dist + 16384);  // 82080 ints
  float* ew   = (float*)(ej + 82080);  // 82080 floats

  hipLaunchKernelGGL(k_dualgemm, dim3(nblk), dim3(256), 0, stream, Xq, Xk, Wq, Wk, part, chunk);
  hipLaunchKernelGGL(k_reduceA,  dim3(RCHUNKS * 32), dim3(256), 0, stream, part, part2, per_chunk);
  hipLaunchKernelGGL(k_reduceB,  dim3(32),   dim3(256), 0, stream, part2, bq, bk, zq, zk);
  hipLaunchKernelGGL(k_norm,     dim3(32),   dim3(128), 0, stream, zq, zk, q, kk, qq, lpos);
  hipLaunchKernelGGL(k_colnorm,  dim3(2),    dim3(256), 0, stream, queue, cn);
  hipLaunchKernelGGL(k_dqq,      dim3(512),  dim3(64),  0, stream, queue, cn, Dqq);
  hipLaunchKernelGGL(k_dot,      dim3(32),   dim3(128), 0, stream, q, queue, qq, cn, dotq, d0);
  hipLaunchKernelGGL(k_top5w,    dim3((BSZ * NN * 64 + 255) / 256), dim3(256), 0, stream, d0, Dqq, ej, ew);
  hipLaunchKernelGGL(k_sssp,     dim3(BSZ),  dim3(256), 0, stream, ej, ew, dist);
  hipLaunchKernelGGL(k_final,    dim3(1),    dim3(512), 0, stream, dist, dotq, lpos, out);
}

// Round 5
// 235.106 us; speedup vs baseline: 2.0164x; 1.1132x over previous
//
#include <hip/hip_runtime.h>
#include <math.h>

#define DIN 50176
#define BSZ 32
#define FEATN 128
#define KQ 512
#define NN 513      // KQ + 1
#define NE (NN * 5) // 2565 edges per batch
#define MM 0.999f
#define ONE_MM 0.001f
#define TT 0.07f
#define RCHUNKS 16  // second-level reduction fan-in

// ---------------- K1: fused dual GEMM, split-K, LDS-broadcast X ----------------
// z_q[b][c] = sum_k Xq[b][k] * Wq[k][c]
// z_k[b][c] = sum_k Xk[b][k] * (M*Wk[k][c] + (1-M)*Wq[k][c])
// Block: 256 threads = 2 c-groups (c = tid&127) x 2 k-half groups (r = tid>>7).
// X chunk staged in LDS once (vector loads), then read as uniform-address
// ds_read_b128 broadcasts (4 k's per op). W rows are coalesced vector loads
// with one-quad manual prefetch. Partials layout identical to before.
__global__ __launch_bounds__(256) void k_dualgemm(
    const float* __restrict__ Xq, const float* __restrict__ Xk,
    const float* __restrict__ Wq, const float* __restrict__ Wk,
    float* __restrict__ part, int chunk, int stride) {
  extern __shared__ float smem[];   // xs[64][stride] overlaid later by red[8*256]
  float* xs = smem;
  const int tid = threadIdx.x;
  const int blk = blockIdx.x;
  const int k0 = blk * chunk;

  // ---- stage X: 64 rows (32 q + 32 k) x chunk floats, float2 loads ----
  {
    const int row = tid >> 2;         // 0..63
    const int q4 = tid & 3;
    const float* src = (row < 32) ? (Xq + (size_t)row * DIN + k0)
                                  : (Xk + (size_t)(row - 32) * DIN + k0);
    float* dst = xs + row * stride;
    const int nf2 = chunk >> 1;
    for (int i = q4; i < nf2; i += 4) {
      const float2 v = *(const float2*)(src + 2 * i);
      *(float2*)(dst + 2 * i) = v;
    }
  }
  __syncthreads();

  // ---- compute: group r handles k-half [r*khalf, (r+1)*khalf) ----
  const int c = tid & 127;
  const int r = tid >> 7;
  const int khalf = chunk >> 1;
  const int kbase = r * khalf;          // local k offset
  const int kg0 = k0 + kbase;           // global k for W rows
  const int nq = khalf >> 2;
  const int rem = khalf & 3;

  float acc[64];
#pragma unroll
  for (int s = 0; s < 64; ++s) acc[s] = 0.f;

  float cwq[4], cwk[4];
  if (nq > 0) {
#pragma unroll
    for (int j = 0; j < 4; ++j) {
      cwq[j] = Wq[(size_t)(kg0 + j) * FEATN + c];
      cwk[j] = Wk[(size_t)(kg0 + j) * FEATN + c];
    }
  }
  for (int iq = 0; iq < nq; ++iq) {
    float nwq[4], nwk[4];
    if (iq + 1 < nq) {                  // uniform branch: prefetch next quad
      const int nk = kg0 + (iq + 1) * 4;
#pragma unroll
      for (int j = 0; j < 4; ++j) {
        nwq[j] = Wq[(size_t)(nk + j) * FEATN + c];
        nwk[j] = Wk[(size_t)(nk + j) * FEATN + c];
      }
    }
    float w2[4];
#pragma unroll
    for (int j = 0; j < 4; ++j) w2[j] = fmaf(MM, cwk[j], ONE_MM * cwq[j]);
    const int kl = kbase + iq * 4;
#pragma unroll
    for (int s = 0; s < 32; ++s) {      // q streams
      const float4 xv = *(const float4*)&xs[s * stride + kl];
      acc[s] = fmaf(xv.x, cwq[0], acc[s]);
      acc[s] = fmaf(xv.y, cwq[1], acc[s]);
      acc[s] = fmaf(xv.z, cwq[2], acc[s]);
      acc[s] = fmaf(xv.w, cwq[3], acc[s]);
    }
#pragma unroll
    for (int s = 0; s < 32; ++s) {      // k streams
      const float4 xv = *(const float4*)&xs[(s + 32) * stride + kl];
      acc[s + 32] = fmaf(xv.x, w2[0], acc[s + 32]);
      acc[s + 32] = fmaf(xv.y, w2[1], acc[s + 32]);
      acc[s + 32] = fmaf(xv.z, w2[2], acc[s + 32]);
      acc[s + 32] = fmaf(xv.w, w2[3], acc[s + 32]);
    }
#pragma unroll
    for (int j = 0; j < 4; ++j) { cwq[j] = nwq[j]; cwk[j] = nwk[j]; }
  }
  for (int t2 = 0; t2 < rem; ++t2) {    // tail k's
    const int kl = kbase + nq * 4 + t2;
    const float wq = Wq[(size_t)(k0 + kl) * FEATN + c];
    const float wk = Wk[(size_t)(k0 + kl) * FEATN + c];
    const float w2 = fmaf(MM, wk, ONE_MM * wq);
#pragma unroll
    for (int s = 0; s < 32; ++s) acc[s] = fmaf(xs[s * stride + kl], wq, acc[s]);
#pragma unroll
    for (int s = 0; s < 32; ++s) acc[s + 32] = fmaf(xs[(s + 32) * stride + kl], w2, acc[s + 32]);
  }

  // ---- reduce the two k-half groups via LDS, write 8192 partials ----
  __syncthreads();                      // all xs reads done; reuse smem as red
  float* red = smem;                    // 8*256 floats
#pragma unroll
  for (int g = 0; g < 8; ++g) {
#pragma unroll
    for (int s = 0; s < 8; ++s) red[s * 256 + tid] = acc[g * 8 + s];
    __syncthreads();
#pragma unroll
    for (int t4 = 0; t4 < 4; ++t4) {
      const int t2 = t4 * 256 + tid;
      const int s = t2 >> 7, c2 = t2 & 127;
      part[(size_t)blk * 8192 + (g * 8 + s) * 128 + c2] =
          red[s * 256 + c2] + red[s * 256 + 128 + c2];
    }
    __syncthreads();
  }
}

// ---------------- K2a: stage-A partial reduction ----------------
__global__ __launch_bounds__(256) void k_reduceA(
    const float* __restrict__ part, float* __restrict__ part2, int per_chunk) {
  const int j = (blockIdx.x & 31) * 256 + threadIdx.x;  // 0..8191
  const int ch = blockIdx.x >> 5;                       // 0..RCHUNKS-1
  const float* p = part + (size_t)ch * per_chunk * 8192 + j;
  float s = 0.f;
  for (int b2 = 0; b2 < per_chunk; ++b2) s += p[(size_t)b2 * 8192];
  part2[(size_t)ch * 8192 + j] = s;
}

// ---------------- K2b: stage-B reduction + bias ----------------
__global__ __launch_bounds__(256) void k_reduceB(
    const float* __restrict__ part2,
    const float* __restrict__ bq, const float* __restrict__ bk,
    float* __restrict__ zq, float* __restrict__ zk) {
  const int j = blockIdx.x * 256 + threadIdx.x;  // 0..8191
  float s = 0.f;
#pragma unroll
  for (int ch = 0; ch < RCHUNKS; ++ch) s += part2[(size_t)ch * 8192 + j];
  const int v = j >> 7, c = j & 127, b = v & 31;
  if (v < 32) zq[b * FEATN + c] = s + bq[c];
  else        zk[b * FEATN + c] = s + fmaf(MM, bk[c], ONE_MM * bq[c]);
}

// ---------------- K3: normalize q,k; qq = sum q^2; l_pos ----------------
__device__ __forceinline__ float red128(float* red, int c, float v) {
  red[c] = v; __syncthreads();
#pragma unroll
  for (int s = 64; s >= 1; s >>= 1) {
    if (c < s) red[c] += red[c + s];
    __syncthreads();
  }
  const float r = red[0];
  __syncthreads();
  return r;
}

__global__ __launch_bounds__(128) void k_norm(
    const float* __restrict__ zq, const float* __restrict__ zk,
    float* __restrict__ q, float* __restrict__ kk,
    float* __restrict__ qq, float* __restrict__ lpos) {
  __shared__ float red[128];
  const int b = blockIdx.x, c = threadIdx.x;
  const float zqv = zq[b * FEATN + c], zkv = zk[b * FEATN + c];
  const float nq = sqrtf(red128(red, c, zqv * zqv));
  const float nk = sqrtf(red128(red, c, zkv * zkv));
  const float qv = zqv / fmaxf(nq, 1e-12f);
  const float kv = zkv / fmaxf(nk, 1e-12f);
  q[b * FEATN + c] = qv;
  kk[b * FEATN + c] = kv;
  const float qsq = red128(red, c, qv * qv);
  const float lp = red128(red, c, qv * kv);
  if (c == 0) { qq[b] = qsq; lpos[b] = lp; }
}

// ---------------- K4a: queue column squared norms ----------------
__global__ __launch_bounds__(256) void k_colnorm(const float* __restrict__ queue,
                                                 float* __restrict__ cn) {
  const int j = blockIdx.x * 256 + threadIdx.x;  // 0..511
  float s = 0.f;
  for (int c = 0; c < FEATN; ++c) { const float t = queue[c * KQ + j]; s = fmaf(t, t, s); }
  cn[j] = s;
}

// ---------------- K4b: queue-queue distances (batch independent) ----------------
__global__ __launch_bounds__(64) void k_dqq(const float* __restrict__ queue,
                                            const float* __restrict__ cn,
                                            float* __restrict__ Dqq) {
  const int i = blockIdx.x, t = threadIdx.x;
  float g[8];
#pragma unroll
  for (int u = 0; u < 8; ++u) g[u] = 0.f;
  for (int c = 0; c < FEATN; ++c) {
    const float qi = queue[c * KQ + i];  // uniform -> scalar
    const float* row = queue + c * KQ;
#pragma unroll
    for (int u = 0; u < 8; ++u) g[u] = fmaf(qi, row[u * 64 + t], g[u]);
  }
  const float cni = cn[i];
#pragma unroll
  for (int u = 0; u < 8; ++u) {
    const int j = u * 64 + t;
    const float d2 = cni + cn[j] - 2.f * g[u];
    Dqq[i * KQ + j] = sqrtf(fmaxf(d2, 0.f));
  }
}

// ---------------- K4c: q.queue dots and q-to-queue distances ----------------
__global__ __launch_bounds__(128) void k_dot(
    const float* __restrict__ q, const float* __restrict__ queue,
    const float* __restrict__ qq, const float* __restrict__ cn,
    float* __restrict__ dotq, float* __restrict__ d0) {
  const int b = blockIdx.x, t = threadIdx.x;
  float g[4];
#pragma unroll
  for (int u = 0; u < 4; ++u) g[u] = 0.f;
  for (int c = 0; c < FEATN; ++c) {
    const float qv = q[b * FEATN + c];  // uniform -> scalar
    const float* row = queue + c * KQ;
#pragma unroll
    for (int u = 0; u < 4; ++u) g[u] = fmaf(qv, row[u * 128 + t], g[u]);
  }
  const float qqb = qq[b];
#pragma unroll
  for (int u = 0; u < 4; ++u) {
    const int j = u * 128 + t;
    dotq[b * KQ + j] = g[u];
    const float d2 = qqb + cn[j] - 2.f * g[u];
    d0[b * KQ + j] = sqrtf(fmaxf(d2, 0.f));
  }
}

// ---------------- K5: per-row top-5-largest, one WAVE per row ----------------
// Reference rule: keep element j iff #{m: d_m > d_j} + #{m > j: d_m == d_j} < 5.
// Equivalent: top-5 under key = (float_bits(d) << 32) | j  (all d >= 0, so
// float bit order == value order; larger index wins ties).
__global__ __launch_bounds__(256) void k_top5w(
    const float* __restrict__ d0, const float* __restrict__ Dqq,
    int* __restrict__ ej, float* __restrict__ ew) {
  const int wid = (blockIdx.x * 256 + threadIdx.x) >> 6;  // row id 0..16415
  const int lane = threadIdx.x & 63;
  if (wid >= BSZ * NN) return;
  const int b = wid / NN, i = wid % NN;
  const float* d0b = d0 + b * KQ;
  const float* Drow = Dqq + (size_t)(i > 0 ? i - 1 : 0) * KQ;

  unsigned long long key[9];
#pragma unroll
  for (int u = 0; u < 9; ++u) {
    const int j = lane + 64 * u;
    const bool valid = (j < NN);
    float vv = 0.f;
    if (valid) {
      if (i == 0) vv = (j == 0) ? 0.f : d0b[j - 1];
      else if (j == 0) vv = d0b[i - 1];
      else vv = Drow[j - 1];
    }
    key[u] = valid
        ? (((unsigned long long)__float_as_uint(vv) << 32) | (unsigned)j)
        : 0ULL;
  }

  unsigned long long r0, r1, r2, r3, r4;
#pragma unroll
  for (int r = 0; r < 5; ++r) {
    unsigned long long m = key[0];
#pragma unroll
    for (int u = 1; u < 9; ++u) m = (key[u] > m) ? key[u] : m;
#pragma unroll
    for (int s = 1; s < 64; s <<= 1) {
      const unsigned long long o = __shfl_xor(m, s, 64);
      m = (o > m) ? o : m;
    }
    if (r == 0) r0 = m; else if (r == 1) r1 = m; else if (r == 2) r2 = m;
    else if (r == 3) r3 = m; else r4 = m;
#pragma unroll
    for (int u = 0; u < 9; ++u) if (key[u] == m) key[u] = 0ULL;
  }

  if (lane < 5) {
    unsigned long long m = r0;
    if (lane == 1) m = r1;
    else if (lane == 2) m = r2;
    else if (lane == 3) m = r3;
    else if (lane == 4) m = r4;
    const float v = __uint_as_float((unsigned)(m >> 32));
    const int idx = (int)(unsigned)(m & 0xffffffffu);
    const int base = wid * 5 + lane;
    ej[base] = (v > 0.f) ? idx : -1;
    ew[base] = v;
  }
}

// ---------------- K6: SSSP from node 0 (Bellman-Ford to fixed point) ----------------
__global__ __launch_bounds__(256) void k_sssp(
    const int* __restrict__ ej, const float* __restrict__ ew,
    float* __restrict__ distout) {
  const int b = blockIdx.x, tid = threadIdx.x;
  __shared__ int dbits[NN];
  __shared__ int sej[NE];
  __shared__ float sew[NE];
  __shared__ int changed;
  for (int e = tid; e < NE; e += 256) { sej[e] = ej[b * NE + e]; sew[e] = ew[b * NE + e]; }
  for (int i = tid; i < NN; i += 256) dbits[i] = (i == 0) ? 0 : 0x7f800000;
  __syncthreads();
  for (int it = 0; it < 600; ++it) {
    if (tid == 0) changed = 0;
    __syncthreads();
    int any = 0;
    for (int e = tid; e < NE; e += 256) {
      const int dst = sej[e];
      if (dst < 0) continue;
      const int sb = dbits[e / 5];
      if (sb == 0x7f800000) continue;
      const float cand = __int_as_float(sb) + sew[e];
      const int cb = __float_as_int(cand);  // nonneg floats: int order == float order
      if (cb < dbits[dst]) { atomicMin(&dbits[dst], cb); any = 1; }
    }
    if (any) atomicOr(&changed, 1);
    __syncthreads();
    if (changed == 0) break;
    __syncthreads();  // protect 'changed' against next-iter reset
  }
  for (int i = tid; i < KQ; i += 256) distout[b * KQ + i] = __int_as_float(dbits[i + 1]);
}

// ---------------- K7: global max, weights, logits, labels ----------------
__global__ __launch_bounds__(512) void k_final(
    const float* __restrict__ dist, const float* __restrict__ dotq,
    const float* __restrict__ lpos, float* __restrict__ out) {
  __shared__ float red[512];
  const int tid = threadIdx.x;
  float mx = 0.f;
  for (int idx = tid; idx < BSZ * KQ; idx += 512) {
    const float d = dist[idx];
    if (d != __builtin_inff()) mx = fmaxf(mx, d);
  }
  red[tid] = mx; __syncthreads();
#pragma unroll
  for (int s = 256; s >= 1; s >>= 1) {
    if (tid < s) red[tid] = fmaxf(red[tid], red[tid + s]);
    __syncthreads();
  }
  const float MX = red[0];
  for (int idx = tid; idx < BSZ * KQ; idx += 512) {
    float d = dist[idx];
    if (d == __builtin_inff()) d = MX + 1.f;
    const float w = 1.f / (1.f + d);
    const int b = idx >> 9, j = idx & 511;
    out[b * NN + 1 + j] = dotq[idx] * w / TT;
  }
  if (tid < BSZ) {
    out[tid * NN] = lpos[tid] / TT;   // l_pos column
    out[BSZ * NN + tid] = 0.f;        // labels: int32 zeros == float 0.0f bits
  }
}

// ---------------- launcher ----------------
extern "C" void kernel_launch(void* const* d_in, const int* in_sizes, int n_in,
                              void* d_out, int out_size, void* d_ws, size_t ws_size,
                              hipStream_t stream) {
  const float* Xq    = (const float*)d_in[0];
  const float* Xk    = (const float*)d_in[1];
  const float* Wq    = (const float*)d_in[2];
  const float* bq    = (const float*)d_in[3];
  const float* Wk    = (const float*)d_in[4];
  const float* bk    = (const float*)d_in[5];
  const float* queue = (const float*)d_in[6];
  float* out = (float*)d_out;
  float* ws = (float*)d_ws;

  const size_t fixed_elems =
      RCHUNKS * 8192 + 4096 * 4 + 32 + 32 + 512 + 262144 + 16384 * 3 + 82080 * 2;
  // pick split-K block count (must divide DIN, %16==0) so everything fits in ws
  const int cand[4] = {784, 512, 256, 128};
  int nblk = 128;
  for (int ci = 0; ci < 4; ++ci) {
    if (((size_t)cand[ci] * 8192 + fixed_elems) * 4 <= ws_size) { nblk = cand[ci]; break; }
  }
  const int chunk = DIN / nblk;                      // 64 / 98 / 196 / 392
  const int stride = (chunk & 3) ? ((chunk + 3) & ~3) : (chunk + 4);  // %4==0, %32!=0
  const size_t smem_bytes = (size_t)64 * stride * 4; // >= 8KB red overlay
  const int per_chunk = nblk / RCHUNKS;

  float* part = ws;
  float* base = ws + (size_t)nblk * 8192;
  float* part2 = base;                   // RCHUNKS * 8192
  float* zq   = part2 + RCHUNKS * 8192;  // 4096
  float* zk   = zq + 4096;
  float* q    = zk + 4096;
  float* kk   = q + 4096;
  float* qq   = kk + 4096;               // 32
  float* lpos = qq + 32;                 // 32
  float* cn   = lpos + 32;               // 512
  float* Dqq  = cn + 512;                // 262144
  float* dotq = Dqq + 262144;            // 16384
  float* d0   = dotq + 16384;            // 16384
  float* dist = d0 + 16384;              // 16384
  int*   ej   = (int*)(dist + 16384);    // 82080 ints
  float* ew   = (float*)(ej + 82080);    // 82080 floats

  hipLaunchKernelGGL(k_dualgemm, dim3(nblk), dim3(256), smem_bytes, stream,
                     Xq, Xk, Wq, Wk, part, chunk, stride);
  hipLaunchKernelGGL(k_reduceA,  dim3(RCHUNKS * 32), dim3(256), 0, stream, part, part2, per_chunk);
  hipLaunchKernelGGL(k_reduceB,  dim3(32),   dim3(256), 0, stream, part2, bq, bk, zq, zk);
  hipLaunchKernelGGL(k_norm,     dim3(32),   dim3(128), 0, stream, zq, zk, q, kk, qq, lpos);
  hipLaunchKernelGGL(k_colnorm,  dim3(2),    dim3(256), 0, stream, queue, cn);
  hipLaunchKernelGGL(k_dqq,      dim3(512),  dim3(64),  0, stream, queue, cn, Dqq);
  hipLaunchKernelGGL(k_dot,      dim3(32),   dim3(128), 0, stream, q, queue, qq, cn, dotq, d0);
  hipLaunchKernelGGL(k_top5w,    dim3((BSZ * NN * 64 + 255) / 256), dim3(256), 0, stream, d0, Dqq, ej, ew);
  hipLaunchKernelGGL(k_sssp,     dim3(BSZ),  dim3(256), 0, stream, ej, ew, dist);
  hipLaunchKernelGGL(k_final,    dim3(1),    dim3(512), 0, stream, dist, dotq, lpos, out);
}

// Round 6
// 215.732 us; speedup vs baseline: 2.1975x; 1.0898x over previous
//
#include <hip/hip_runtime.h>
#include <math.h>

#define DIN 50176
#define BSZ 32
#define FEATN 128
#define KQ 512
#define NN 513      // KQ + 1
#define NE (NN * 5) // 2565 edges per batch
#define MM 0.999f
#define ONE_MM 0.001f
#define TT 0.07f
#define RCHUNKS 16  // second-level reduction fan-in
#define KT 64       // X k-tile per block iteration
#define KW 32       // W k-half staged in LDS

// ---------------- K1: fused dual GEMM, register-tiled, LDS-staged ----------------
// z_q[b][c] = sum_k Xq[b][k] * Wq[k][c]
// z_k[b][c] = sum_k Xk[b][k] * (M*Wk[k][c] + (1-M)*Wq[k][c])
// 256 threads: cg = tid&31 (c = 4*cg), rg = tid>>5 (rows 8rg..8rg+7).
// Rows 0..31 = q-streams (weight wq), rows 32..63 = k-streams (weight w2,
// momentum-combined at staging time). Thread acc = 8 rows x 4 cols.
// Per k: 2 broadcast ds_read_b128 (X) + 1 ds_read_b128 (W) + 32 FMA -> VALU-bound.
// No k-split across threads => acc is the final block partial (no LDS epilogue).
__global__ __launch_bounds__(256) void k_dualgemm(
    const float* __restrict__ Xq, const float* __restrict__ Xk,
    const float* __restrict__ Wq, const float* __restrict__ Wk,
    float* __restrict__ part, int chunk) {
  __shared__ float xs[KT * 64];     // [k][row], stride 64 (bank = row%32, 2-way free)
  __shared__ float wsq[KW * 128];   // [k][c] raw Wq
  __shared__ float ws2[KW * 128];   // [k][c] momentum-combined
  const int tid = threadIdx.x;
  const int blk = blockIdx.x;
  const int k0 = blk * chunk;

  const int cg = tid & 31;
  const int rg = tid >> 5;
  const int xrow0 = rg * 8;
  const float* wsp = (rg < 4) ? wsq : ws2;   // wave-uniform select

  float acc[8][4];
#pragma unroll
  for (int r = 0; r < 8; ++r)
#pragma unroll
    for (int j = 0; j < 4; ++j) acc[r][j] = 0.f;

  // X staging ids: q-major items -> conflict-free transposed LDS writes
  const int srow = tid & 63;
  const int sqb = tid >> 6;  // 0..3
  const float* xsrc = (srow < 32) ? (Xq + (size_t)srow * DIN)
                                  : (Xk + (size_t)(srow - 32) * DIN);
  // W staging ids: item = k*32 + cq
  const int wk0 = tid >> 5;        // k = wk0 + 8u
  const int wcq = (tid & 31) * 4;  // c quad

  const int T = chunk / KT;
  for (int t = 0; t < T; ++t) {
    const int kt = k0 + t * KT;

    // ---- stage X tile (transposed): 4 float4 loads, 16 b32 writes ----
#pragma unroll
    for (int u = 0; u < 4; ++u) {
      const int q = sqb + 4 * u;                       // k-quad 0..15
      const float4 v = *(const float4*)(xsrc + kt + 4 * q);
      xs[(4 * q + 0) * 64 + srow] = v.x;
      xs[(4 * q + 1) * 64 + srow] = v.y;
      xs[(4 * q + 2) * 64 + srow] = v.z;
      xs[(4 * q + 3) * 64 + srow] = v.w;
    }
    // ---- stage W half 0 (combine momentum during staging) ----
    float4 aq[4], ak[4];
#pragma unroll
    for (int u = 0; u < 4; ++u) {
      const size_t g = (size_t)(kt + wk0 + 8 * u) * FEATN + wcq;
      aq[u] = *(const float4*)(Wq + g);
      ak[u] = *(const float4*)(Wk + g);
    }
#pragma unroll
    for (int u = 0; u < 4; ++u) {
      const int off = (wk0 + 8 * u) * 128 + wcq;
      *(float4*)&wsq[off] = aq[u];
      float4 w2;
      w2.x = fmaf(MM, ak[u].x, ONE_MM * aq[u].x);
      w2.y = fmaf(MM, ak[u].y, ONE_MM * aq[u].y);
      w2.z = fmaf(MM, ak[u].z, ONE_MM * aq[u].z);
      w2.w = fmaf(MM, ak[u].w, ONE_MM * aq[u].w);
      *(float4*)&ws2[off] = w2;
    }
    __syncthreads();

    // ---- issue W half-1 global loads early (hide under compute h0) ----
#pragma unroll
    for (int u = 0; u < 4; ++u) {
      const size_t g = (size_t)(kt + KW + wk0 + 8 * u) * FEATN + wcq;
      aq[u] = *(const float4*)(Wq + g);
      ak[u] = *(const float4*)(Wk + g);
    }

    // ---- compute half 0: k = 0..KW-1 ----
#pragma unroll 4
    for (int kk = 0; kk < KW; ++kk) {
      const float4 x0 = *(const float4*)&xs[kk * 64 + xrow0];
      const float4 x1 = *(const float4*)&xs[kk * 64 + xrow0 + 4];
      const float4 w = *(const float4*)&wsp[kk * 128 + wcq * 0 + 4 * cg];
      acc[0][0] = fmaf(x0.x, w.x, acc[0][0]); acc[0][1] = fmaf(x0.x, w.y, acc[0][1]);
      acc[0][2] = fmaf(x0.x, w.z, acc[0][2]); acc[0][3] = fmaf(x0.x, w.w, acc[0][3]);
      acc[1][0] = fmaf(x0.y, w.x, acc[1][0]); acc[1][1] = fmaf(x0.y, w.y, acc[1][1]);
      acc[1][2] = fmaf(x0.y, w.z, acc[1][2]); acc[1][3] = fmaf(x0.y, w.w, acc[1][3]);
      acc[2][0] = fmaf(x0.z, w.x, acc[2][0]); acc[2][1] = fmaf(x0.z, w.y, acc[2][1]);
      acc[2][2] = fmaf(x0.z, w.z, acc[2][2]); acc[2][3] = fmaf(x0.z, w.w, acc[2][3]);
      acc[3][0] = fmaf(x0.w, w.x, acc[3][0]); acc[3][1] = fmaf(x0.w, w.y, acc[3][1]);
      acc[3][2] = fmaf(x0.w, w.z, acc[3][2]); acc[3][3] = fmaf(x0.w, w.w, acc[3][3]);
      acc[4][0] = fmaf(x1.x, w.x, acc[4][0]); acc[4][1] = fmaf(x1.x, w.y, acc[4][1]);
      acc[4][2] = fmaf(x1.x, w.z, acc[4][2]); acc[4][3] = fmaf(x1.x, w.w, acc[4][3]);
      acc[5][0] = fmaf(x1.y, w.x, acc[5][0]); acc[5][1] = fmaf(x1.y, w.y, acc[5][1]);
      acc[5][2] = fmaf(x1.y, w.z, acc[5][2]); acc[5][3] = fmaf(x1.y, w.w, acc[5][3]);
      acc[6][0] = fmaf(x1.z, w.x, acc[6][0]); acc[6][1] = fmaf(x1.z, w.y, acc[6][1]);
      acc[6][2] = fmaf(x1.z, w.z, acc[6][2]); acc[6][3] = fmaf(x1.z, w.w, acc[6][3]);
      acc[7][0] = fmaf(x1.w, w.x, acc[7][0]); acc[7][1] = fmaf(x1.w, w.y, acc[7][1]);
      acc[7][2] = fmaf(x1.w, w.z, acc[7][2]); acc[7][3] = fmaf(x1.w, w.w, acc[7][3]);
    }
    __syncthreads();

    // ---- write W half 1 to LDS ----
#pragma unroll
    for (int u = 0; u < 4; ++u) {
      const int off = (wk0 + 8 * u) * 128 + wcq;
      *(float4*)&wsq[off] = aq[u];
      float4 w2;
      w2.x = fmaf(MM, ak[u].x, ONE_MM * aq[u].x);
      w2.y = fmaf(MM, ak[u].y, ONE_MM * aq[u].y);
      w2.z = fmaf(MM, ak[u].z, ONE_MM * aq[u].z);
      w2.w = fmaf(MM, ak[u].w, ONE_MM * aq[u].w);
      *(float4*)&ws2[off] = w2;
    }
    __syncthreads();

    // ---- compute half 1: k = KW..KT-1 ----
#pragma unroll 4
    for (int kk = 0; kk < KW; ++kk) {
      const float4 x0 = *(const float4*)&xs[(KW + kk) * 64 + xrow0];
      const float4 x1 = *(const float4*)&xs[(KW + kk) * 64 + xrow0 + 4];
      const float4 w = *(const float4*)&wsp[kk * 128 + 4 * cg];
      acc[0][0] = fmaf(x0.x, w.x, acc[0][0]); acc[0][1] = fmaf(x0.x, w.y, acc[0][1]);
      acc[0][2] = fmaf(x0.x, w.z, acc[0][2]); acc[0][3] = fmaf(x0.x, w.w, acc[0][3]);
      acc[1][0] = fmaf(x0.y, w.x, acc[1][0]); acc[1][1] = fmaf(x0.y, w.y, acc[1][1]);
      acc[1][2] = fmaf(x0.y, w.z, acc[1][2]); acc[1][3] = fmaf(x0.y, w.w, acc[1][3]);
      acc[2][0] = fmaf(x0.z, w.x, acc[2][0]); acc[2][1] = fmaf(x0.z, w.y, acc[2][1]);
      acc[2][2] = fmaf(x0.z, w.z, acc[2][2]); acc[2][3] = fmaf(x0.z, w.w, acc[2][3]);
      acc[3][0] = fmaf(x0.w, w.x, acc[3][0]); acc[3][1] = fmaf(x0.w, w.y, acc[3][1]);
      acc[3][2] = fmaf(x0.w, w.z, acc[3][2]); acc[3][3] = fmaf(x0.w, w.w, acc[3][3]);
      acc[4][0] = fmaf(x1.x, w.x, acc[4][0]); acc[4][1] = fmaf(x1.x, w.y, acc[4][1]);
      acc[4][2] = fmaf(x1.x, w.z, acc[4][2]); acc[4][3] = fmaf(x1.x, w.w, acc[4][3]);
      acc[5][0] = fmaf(x1.y, w.x, acc[5][0]); acc[5][1] = fmaf(x1.y, w.y, acc[5][1]);
      acc[5][2] = fmaf(x1.y, w.z, acc[5][2]); acc[5][3] = fmaf(x1.y, w.w, acc[5][3]);
      acc[6][0] = fmaf(x1.z, w.x, acc[6][0]); acc[6][1] = fmaf(x1.z, w.y, acc[6][1]);
      acc[6][2] = fmaf(x1.z, w.z, acc[6][2]); acc[6][3] = fmaf(x1.z, w.w, acc[6][3]);
      acc[7][0] = fmaf(x1.w, w.x, acc[7][0]); acc[7][1] = fmaf(x1.w, w.y, acc[7][1]);
      acc[7][2] = fmaf(x1.w, w.z, acc[7][2]); acc[7][3] = fmaf(x1.w, w.w, acc[7][3]);
    }
    __syncthreads();   // protect xs/ws before next tile restage
  }

  // ---- write partials: same layout as before (row*128 + c) ----
  float* p = part + (size_t)blk * 8192;
#pragma unroll
  for (int r = 0; r < 8; ++r) {
    float4 v;
    v.x = acc[r][0]; v.y = acc[r][1]; v.z = acc[r][2]; v.w = acc[r][3];
    *(float4*)&p[(xrow0 + r) * 128 + 4 * cg] = v;
  }
}

// ---------------- K2a: stage-A partial reduction (float4) ----------------
__global__ __launch_bounds__(256) void k_reduceA(
    const float* __restrict__ part, float* __restrict__ part2, int per_chunk) {
  const int j4 = (blockIdx.x & 7) * 256 + threadIdx.x;  // 0..2047
  const int ch = blockIdx.x >> 3;                       // 0..RCHUNKS-1
  const float4* p = (const float4*)part + (size_t)ch * per_chunk * 2048 + j4;
  float4 s = {0.f, 0.f, 0.f, 0.f};
  for (int b = 0; b < per_chunk; ++b) {
    const float4 v = p[(size_t)b * 2048];
    s.x += v.x; s.y += v.y; s.z += v.z; s.w += v.w;
  }
  ((float4*)part2)[(size_t)ch * 2048 + j4] = s;
}

// ---------------- K2b: stage-B reduction + bias (float4) ----------------
__global__ __launch_bounds__(256) void k_reduceB(
    const float* __restrict__ part2,
    const float* __restrict__ bq, const float* __restrict__ bk,
    float* __restrict__ zq, float* __restrict__ zk) {
  const int j4 = blockIdx.x * 256 + threadIdx.x;  // 0..2047
  float4 s = {0.f, 0.f, 0.f, 0.f};
#pragma unroll
  for (int ch = 0; ch < RCHUNKS; ++ch) {
    const float4 v = ((const float4*)part2)[(size_t)ch * 2048 + j4];
    s.x += v.x; s.y += v.y; s.z += v.z; s.w += v.w;
  }
  const int v = j4 >> 5;            // stream 0..63
  const int c0 = (j4 & 31) * 4;     // col quad
  const int b = v & 31;
  if (v < 32) {
    s.x += bq[c0 + 0]; s.y += bq[c0 + 1]; s.z += bq[c0 + 2]; s.w += bq[c0 + 3];
    *(float4*)&zq[b * FEATN + c0] = s;
  } else {
    s.x += fmaf(MM, bk[c0 + 0], ONE_MM * bq[c0 + 0]);
    s.y += fmaf(MM, bk[c0 + 1], ONE_MM * bq[c0 + 1]);
    s.z += fmaf(MM, bk[c0 + 2], ONE_MM * bq[c0 + 2]);
    s.w += fmaf(MM, bk[c0 + 3], ONE_MM * bq[c0 + 3]);
    *(float4*)&zk[b * FEATN + c0] = s;
  }
}

// ---------------- K3: normalize q,k; qq = sum q^2; l_pos ----------------
__device__ __forceinline__ float red128(float* red, int c, float v) {
  red[c] = v; __syncthreads();
#pragma unroll
  for (int s = 64; s >= 1; s >>= 1) {
    if (c < s) red[c] += red[c + s];
    __syncthreads();
  }
  const float r = red[0];
  __syncthreads();
  return r;
}

__global__ __launch_bounds__(128) void k_norm(
    const float* __restrict__ zq, const float* __restrict__ zk,
    float* __restrict__ q, float* __restrict__ kk,
    float* __restrict__ qq, float* __restrict__ lpos) {
  __shared__ float red[128];
  const int b = blockIdx.x, c = threadIdx.x;
  const float zqv = zq[b * FEATN + c], zkv = zk[b * FEATN + c];
  const float nq = sqrtf(red128(red, c, zqv * zqv));
  const float nk = sqrtf(red128(red, c, zkv * zkv));
  const float qv = zqv / fmaxf(nq, 1e-12f);
  const float kv = zkv / fmaxf(nk, 1e-12f);
  q[b * FEATN + c] = qv;
  kk[b * FEATN + c] = kv;
  const float qsq = red128(red, c, qv * qv);
  const float lp = red128(red, c, qv * kv);
  if (c == 0) { qq[b] = qsq; lpos[b] = lp; }
}

// ---------------- K4a: queue column squared norms ----------------
__global__ __launch_bounds__(256) void k_colnorm(const float* __restrict__ queue,
                                                 float* __restrict__ cn) {
  const int j = blockIdx.x * 256 + threadIdx.x;  // 0..511
  float s = 0.f;
  for (int c = 0; c < FEATN; ++c) { const float t = queue[c * KQ + j]; s = fmaf(t, t, s); }
  cn[j] = s;
}

// ---------------- K4b: queue-queue distances (batch independent) ----------------
__global__ __launch_bounds__(64) void k_dqq(const float* __restrict__ queue,
                                            const float* __restrict__ cn,
                                            float* __restrict__ Dqq) {
  const int i = blockIdx.x, t = threadIdx.x;
  float g[8];
#pragma unroll
  for (int u = 0; u < 8; ++u) g[u] = 0.f;
  for (int c = 0; c < FEATN; ++c) {
    const float qi = queue[c * KQ + i];  // uniform -> scalar
    const float* row = queue + c * KQ;
#pragma unroll
    for (int u = 0; u < 8; ++u) g[u] = fmaf(qi, row[u * 64 + t], g[u]);
  }
  const float cni = cn[i];
#pragma unroll
  for (int u = 0; u < 8; ++u) {
    const int j = u * 64 + t;
    const float d2 = cni + cn[j] - 2.f * g[u];
    Dqq[i * KQ + j] = sqrtf(fmaxf(d2, 0.f));
  }
}

// ---------------- K4c: q.queue dots and q-to-queue distances ----------------
__global__ __launch_bounds__(128) void k_dot(
    const float* __restrict__ q, const float* __restrict__ queue,
    const float* __restrict__ qq, const float* __restrict__ cn,
    float* __restrict__ dotq, float* __restrict__ d0) {
  const int b = blockIdx.x, t = threadIdx.x;
  float g[4];
#pragma unroll
  for (int u = 0; u < 4; ++u) g[u] = 0.f;
  for (int c = 0; c < FEATN; ++c) {
    const float qv = q[b * FEATN + c];  // uniform -> scalar
    const float* row = queue + c * KQ;
#pragma unroll
    for (int u = 0; u < 4; ++u) g[u] = fmaf(qv, row[u * 128 + t], g[u]);
  }
  const float qqb = qq[b];
#pragma unroll
  for (int u = 0; u < 4; ++u) {
    const int j = u * 128 + t;
    dotq[b * KQ + j] = g[u];
    const float d2 = qqb + cn[j] - 2.f * g[u];
    d0[b * KQ + j] = sqrtf(fmaxf(d2, 0.f));
  }
}

// ---------------- K5: per-row top-5-largest, one WAVE per row ----------------
// Reference rule: keep element j iff #{m: d_m > d_j} + #{m > j: d_m == d_j} < 5.
// Equivalent: top-5 under key = (float_bits(d) << 32) | j  (all d >= 0, so
// float bit order == value order; larger index wins ties).
__global__ __launch_bounds__(256) void k_top5w(
    const float* __restrict__ d0, const float* __restrict__ Dqq,
    int* __restrict__ ej, float* __restrict__ ew) {
  const int wid = (blockIdx.x * 256 + threadIdx.x) >> 6;  // row id 0..16415
  const int lane = threadIdx.x & 63;
  if (wid >= BSZ * NN) return;
  const int b = wid / NN, i = wid % NN;
  const float* d0b = d0 + b * KQ;
  const float* Drow = Dqq + (size_t)(i > 0 ? i - 1 : 0) * KQ;

  unsigned long long key[9];
#pragma unroll
  for (int u = 0; u < 9; ++u) {
    const int j = lane + 64 * u;
    const bool valid = (j < NN);
    float vv = 0.f;
    if (valid) {
      if (i == 0) vv = (j == 0) ? 0.f : d0b[j - 1];
      else if (j == 0) vv = d0b[i - 1];
      else vv = Drow[j - 1];
    }
    key[u] = valid
        ? (((unsigned long long)__float_as_uint(vv) << 32) | (unsigned)j)
        : 0ULL;
  }

  unsigned long long r0, r1, r2, r3, r4;
#pragma unroll
  for (int r = 0; r < 5; ++r) {
    unsigned long long m = key[0];
#pragma unroll
    for (int u = 1; u < 9; ++u) m = (key[u] > m) ? key[u] : m;
#pragma unroll
    for (int s = 1; s < 64; s <<= 1) {
      const unsigned long long o = __shfl_xor(m, s, 64);
      m = (o > m) ? o : m;
    }
    if (r == 0) r0 = m; else if (r == 1) r1 = m; else if (r == 2) r2 = m;
    else if (r == 3) r3 = m; else r4 = m;
#pragma unroll
    for (int u = 0; u < 9; ++u) if (key[u] == m) key[u] = 0ULL;
  }

  if (lane < 5) {
    unsigned long long m = r0;
    if (lane == 1) m = r1;
    else if (lane == 2) m = r2;
    else if (lane == 3) m = r3;
    else if (lane == 4) m = r4;
    const float v = __uint_as_float((unsigned)(m >> 32));
    const int idx = (int)(unsigned)(m & 0xffffffffu);
    const int base = wid * 5 + lane;
    ej[base] = (v > 0.f) ? idx : -1;
    ew[base] = v;
  }
}

// ---------------- K6: SSSP from node 0 (Bellman-Ford to fixed point) ----------------
__global__ __launch_bounds__(256) void k_sssp(
    const int* __restrict__ ej, const float* __restrict__ ew,
    float* __restrict__ distout) {
  const int b = blockIdx.x, tid = threadIdx.x;
  __shared__ int dbits[NN];
  __shared__ int sej[NE];
  __shared__ float sew[NE];
  __shared__ int changed;
  for (int e = tid; e < NE; e += 256) { sej[e] = ej[b * NE + e]; sew[e] = ew[b * NE + e]; }
  for (int i = tid; i < NN; i += 256) dbits[i] = (i == 0) ? 0 : 0x7f800000;
  __syncthreads();
  for (int it = 0; it < 600; ++it) {
    if (tid == 0) changed = 0;
    __syncthreads();
    int any = 0;
    for (int e = tid; e < NE; e += 256) {
      const int dst = sej[e];
      if (dst < 0) continue;
      const int sb = dbits[e / 5];
      if (sb == 0x7f800000) continue;
      const float cand = __int_as_float(sb) + sew[e];
      const int cb = __float_as_int(cand);  // nonneg floats: int order == float order
      if (cb < dbits[dst]) { atomicMin(&dbits[dst], cb); any = 1; }
    }
    if (any) atomicOr(&changed, 1);
    __syncthreads();
    if (changed == 0) break;
    __syncthreads();  // protect 'changed' against next-iter reset
  }
  for (int i = tid; i < KQ; i += 256) distout[b * KQ + i] = __int_as_float(dbits[i + 1]);
}

// ---------------- K7: global max, weights, logits, labels ----------------
__global__ __launch_bounds__(512) void k_final(
    const float* __restrict__ dist, const float* __restrict__ dotq,
    const float* __restrict__ lpos, float* __restrict__ out) {
  __shared__ float red[512];
  const int tid = threadIdx.x;
  float mx = 0.f;
  for (int idx = tid; idx < BSZ * KQ; idx += 512) {
    const float d = dist[idx];
    if (d != __builtin_inff()) mx = fmaxf(mx, d);
  }
  red[tid] = mx; __syncthreads();
#pragma unroll
  for (int s = 256; s >= 1; s >>= 1) {
    if (tid < s) red[tid] = fmaxf(red[tid], red[tid + s]);
    __syncthreads();
  }
  const float MX = red[0];
  for (int idx = tid; idx < BSZ * KQ; idx += 512) {
    float d = dist[idx];
    if (d == __builtin_inff()) d = MX + 1.f;
    const float w = 1.f / (1.f + d);
    const int b = idx >> 9, j = idx & 511;
    out[b * NN + 1 + j] = dotq[idx] * w / TT;
  }
  if (tid < BSZ) {
    out[tid * NN] = lpos[tid] / TT;   // l_pos column
    out[BSZ * NN + tid] = 0.f;        // labels: int32 zeros == float 0.0f bits
  }
}

// ---------------- launcher ----------------
extern "C" void kernel_launch(void* const* d_in, const int* in_sizes, int n_in,
                              void* d_out, int out_size, void* d_ws, size_t ws_size,
                              hipStream_t stream) {
  const float* Xq    = (const float*)d_in[0];
  const float* Xk    = (const float*)d_in[1];
  const float* Wq    = (const float*)d_in[2];
  const float* bq    = (const float*)d_in[3];
  const float* Wk    = (const float*)d_in[4];
  const float* bk    = (const float*)d_in[5];
  const float* queue = (const float*)d_in[6];
  float* out = (float*)d_out;
  float* ws = (float*)d_ws;

  const size_t fixed_elems =
      RCHUNKS * 8192 + 4096 * 4 + 32 + 32 + 512 + 262144 + 16384 * 3 + 82080 * 2;
  // split-K block count: chunk = DIN/nblk must be a multiple of KT=64,
  // nblk must be a multiple of RCHUNKS. Candidates sized to fit ws.
  const int cand[3] = {784, 112, 16};
  int nblk = 16;
  for (int ci = 0; ci < 3; ++ci) {
    if (((size_t)cand[ci] * 8192 + fixed_elems) * 4 <= ws_size) { nblk = cand[ci]; break; }
  }
  const int chunk = DIN / nblk;  // 64 / 448 / 3136
  const int per_chunk = nblk / RCHUNKS;

  float* part = ws;
  float* base = ws + (size_t)nblk * 8192;
  float* part2 = base;                   // RCHUNKS * 8192
  float* zq   = part2 + RCHUNKS * 8192;  // 4096
  float* zk   = zq + 4096;
  float* q    = zk + 4096;
  float* kk   = q + 4096;
  float* qq   = kk + 4096;               // 32
  float* lpos = qq + 32;                 // 32
  float* cn   = lpos + 32;               // 512
  float* Dqq  = cn + 512;                // 262144
  float* dotq = Dqq + 262144;            // 16384
  float* d0   = dotq + 16384;            // 16384
  float* dist = d0 + 16384;              // 16384
  int*   ej   = (int*)(dist + 16384);    // 82080 ints
  float* ew   = (float*)(ej + 82080);    // 82080 floats

  hipLaunchKernelGGL(k_dualgemm, dim3(nblk), dim3(256), 0, stream, Xq, Xk, Wq, Wk, part, chunk);
  hipLaunchKernelGGL(k_reduceA,  dim3(RCHUNKS * 8), dim3(256), 0, stream, part, part2, per_chunk);
  hipLaunchKernelGGL(k_reduceB,  dim3(8),    dim3(256), 0, stream, part2, bq, bk, zq, zk);
  hipLaunchKernelGGL(k_norm,     dim3(32),   dim3(128), 0, stream, zq, zk, q, kk, qq, lpos);
  hipLaunchKernelGGL(k_colnorm,  dim3(2),    dim3(256), 0, stream, queue, cn);
  hipLaunchKernelGGL(k_dqq,      dim3(512),  dim3(64),  0, stream, queue, cn, Dqq);
  hipLaunchKernelGGL(k_dot,      dim3(32),   dim3(128), 0, stream, q, queue, qq, cn, dotq, d0);
  hipLaunchKernelGGL(k_top5w,    dim3((BSZ * NN * 64 + 255) / 256), dim3(256), 0, stream, d0, Dqq, ej, ew);
  hipLaunchKernelGGL(k_sssp,     dim3(BSZ),  dim3(256), 0, stream, ej, ew, dist);
  hipLaunchKernelGGL(k_final,    dim3(1),    dim3(512), 0, stream, dist, dotq, lpos, out);
}

// Round 7
// 208.329 us; speedup vs baseline: 2.2756x; 1.0355x over previous
//
#include <hip/hip_runtime.h>
#include <math.h>

#define DIN 50176
#define BSZ 32
#define FEATN 128
#define KQ 512
#define NN 513      // KQ + 1
#define NE (NN * 5) // 2565 edges per batch
#define MM 0.999f
#define ONE_MM 0.001f
#define TT 0.07f
#define RCHUNKS 16  // second-level reduction fan-in
#define KT 64       // X k-tile per block iteration
#define KW 32       // W k-half staged in LDS

// ---------------- K1: fused dual GEMM, register-tiled, LDS-staged ----------------
// (unchanged from round 6 — not visible in top-5, left alone for attribution)
__global__ __launch_bounds__(256) void k_dualgemm(
    const float* __restrict__ Xq, const float* __restrict__ Xk,
    const float* __restrict__ Wq, const float* __restrict__ Wk,
    float* __restrict__ part, int chunk) {
  __shared__ float xs[KT * 64];     // [k][row]
  __shared__ float wsq[KW * 128];   // [k][c] raw Wq
  __shared__ float ws2[KW * 128];   // [k][c] momentum-combined
  const int tid = threadIdx.x;
  const int blk = blockIdx.x;
  const int k0 = blk * chunk;

  const int cg = tid & 31;
  const int rg = tid >> 5;
  const int xrow0 = rg * 8;
  const float* wsp = (rg < 4) ? wsq : ws2;   // wave-uniform select

  float acc[8][4];
#pragma unroll
  for (int r = 0; r < 8; ++r)
#pragma unroll
    for (int j = 0; j < 4; ++j) acc[r][j] = 0.f;

  const int srow = tid & 63;
  const int sqb = tid >> 6;  // 0..3
  const float* xsrc = (srow < 32) ? (Xq + (size_t)srow * DIN)
                                  : (Xk + (size_t)(srow - 32) * DIN);
  const int wk0 = tid >> 5;        // k = wk0 + 8u
  const int wcq = (tid & 31) * 4;  // c quad

  const int T = chunk / KT;
  for (int t = 0; t < T; ++t) {
    const int kt = k0 + t * KT;

#pragma unroll
    for (int u = 0; u < 4; ++u) {
      const int q = sqb + 4 * u;                       // k-quad 0..15
      const float4 v = *(const float4*)(xsrc + kt + 4 * q);
      xs[(4 * q + 0) * 64 + srow] = v.x;
      xs[(4 * q + 1) * 64 + srow] = v.y;
      xs[(4 * q + 2) * 64 + srow] = v.z;
      xs[(4 * q + 3) * 64 + srow] = v.w;
    }
    float4 aq[4], ak[4];
#pragma unroll
    for (int u = 0; u < 4; ++u) {
      const size_t g = (size_t)(kt + wk0 + 8 * u) * FEATN + wcq;
      aq[u] = *(const float4*)(Wq + g);
      ak[u] = *(const float4*)(Wk + g);
    }
#pragma unroll
    for (int u = 0; u < 4; ++u) {
      const int off = (wk0 + 8 * u) * 128 + wcq;
      *(float4*)&wsq[off] = aq[u];
      float4 w2;
      w2.x = fmaf(MM, ak[u].x, ONE_MM * aq[u].x);
      w2.y = fmaf(MM, ak[u].y, ONE_MM * aq[u].y);
      w2.z = fmaf(MM, ak[u].z, ONE_MM * aq[u].z);
      w2.w = fmaf(MM, ak[u].w, ONE_MM * aq[u].w);
      *(float4*)&ws2[off] = w2;
    }
    __syncthreads();

#pragma unroll
    for (int u = 0; u < 4; ++u) {
      const size_t g = (size_t)(kt + KW + wk0 + 8 * u) * FEATN + wcq;
      aq[u] = *(const float4*)(Wq + g);
      ak[u] = *(const float4*)(Wk + g);
    }

#pragma unroll 4
    for (int kk = 0; kk < KW; ++kk) {
      const float4 x0 = *(const float4*)&xs[kk * 64 + xrow0];
      const float4 x1 = *(const float4*)&xs[kk * 64 + xrow0 + 4];
      const float4 w = *(const float4*)&wsp[kk * 128 + 4 * cg];
      acc[0][0] = fmaf(x0.x, w.x, acc[0][0]); acc[0][1] = fmaf(x0.x, w.y, acc[0][1]);
      acc[0][2] = fmaf(x0.x, w.z, acc[0][2]); acc[0][3] = fmaf(x0.x, w.w, acc[0][3]);
      acc[1][0] = fmaf(x0.y, w.x, acc[1][0]); acc[1][1] = fmaf(x0.y, w.y, acc[1][1]);
      acc[1][2] = fmaf(x0.y, w.z, acc[1][2]); acc[1][3] = fmaf(x0.y, w.w, acc[1][3]);
      acc[2][0] = fmaf(x0.z, w.x, acc[2][0]); acc[2][1] = fmaf(x0.z, w.y, acc[2][1]);
      acc[2][2] = fmaf(x0.z, w.z, acc[2][2]); acc[2][3] = fmaf(x0.z, w.w, acc[2][3]);
      acc[3][0] = fmaf(x0.w, w.x, acc[3][0]); acc[3][1] = fmaf(x0.w, w.y, acc[3][1]);
      acc[3][2] = fmaf(x0.w, w.z, acc[3][2]); acc[3][3] = fmaf(x0.w, w.w, acc[3][3]);
      acc[4][0] = fmaf(x1.x, w.x, acc[4][0]); acc[4][1] = fmaf(x1.x, w.y, acc[4][1]);
      acc[4][2] = fmaf(x1.x, w.z, acc[4][2]); acc[4][3] = fmaf(x1.x, w.w, acc[4][3]);
      acc[5][0] = fmaf(x1.y, w.x, acc[5][0]); acc[5][1] = fmaf(x1.y, w.y, acc[5][1]);
      acc[5][2] = fmaf(x1.y, w.z, acc[5][2]); acc[5][3] = fmaf(x1.y, w.w, acc[5][3]);
      acc[6][0] = fmaf(x1.z, w.x, acc[6][0]); acc[6][1] = fmaf(x1.z, w.y, acc[6][1]);
      acc[6][2] = fmaf(x1.z, w.z, acc[6][2]); acc[6][3] = fmaf(x1.z, w.w, acc[6][3]);
      acc[7][0] = fmaf(x1.w, w.x, acc[7][0]); acc[7][1] = fmaf(x1.w, w.y, acc[7][1]);
      acc[7][2] = fmaf(x1.w, w.z, acc[7][2]); acc[7][3] = fmaf(x1.w, w.w, acc[7][3]);
    }
    __syncthreads();

#pragma unroll
    for (int u = 0; u < 4; ++u) {
      const int off = (wk0 + 8 * u) * 128 + wcq;
      *(float4*)&wsq[off] = aq[u];
      float4 w2;
      w2.x = fmaf(MM, ak[u].x, ONE_MM * aq[u].x);
      w2.y = fmaf(MM, ak[u].y, ONE_MM * aq[u].y);
      w2.z = fmaf(MM, ak[u].z, ONE_MM * aq[u].z);
      w2.w = fmaf(MM, ak[u].w, ONE_MM * aq[u].w);
      *(float4*)&ws2[off] = w2;
    }
    __syncthreads();

#pragma unroll 4
    for (int kk = 0; kk < KW; ++kk) {
      const float4 x0 = *(const float4*)&xs[(KW + kk) * 64 + xrow0];
      const float4 x1 = *(const float4*)&xs[(KW + kk) * 64 + xrow0 + 4];
      const float4 w = *(const float4*)&wsp[kk * 128 + 4 * cg];
      acc[0][0] = fmaf(x0.x, w.x, acc[0][0]); acc[0][1] = fmaf(x0.x, w.y, acc[0][1]);
      acc[0][2] = fmaf(x0.x, w.z, acc[0][2]); acc[0][3] = fmaf(x0.x, w.w, acc[0][3]);
      acc[1][0] = fmaf(x0.y, w.x, acc[1][0]); acc[1][1] = fmaf(x0.y, w.y, acc[1][1]);
      acc[1][2] = fmaf(x0.y, w.z, acc[1][2]); acc[1][3] = fmaf(x0.y, w.w, acc[1][3]);
      acc[2][0] = fmaf(x0.z, w.x, acc[2][0]); acc[2][1] = fmaf(x0.z, w.y, acc[2][1]);
      acc[2][2] = fmaf(x0.z, w.z, acc[2][2]); acc[2][3] = fmaf(x0.z, w.w, acc[2][3]);
      acc[3][0] = fmaf(x0.w, w.x, acc[3][0]); acc[3][1] = fmaf(x0.w, w.y, acc[3][1]);
      acc[3][2] = fmaf(x0.w, w.z, acc[3][2]); acc[3][3] = fmaf(x0.w, w.w, acc[3][3]);
      acc[4][0] = fmaf(x1.x, w.x, acc[4][0]); acc[4][1] = fmaf(x1.x, w.y, acc[4][1]);
      acc[4][2] = fmaf(x1.x, w.z, acc[4][2]); acc[4][3] = fmaf(x1.x, w.w, acc[4][3]);
      acc[5][0] = fmaf(x1.y, w.x, acc[5][0]); acc[5][1] = fmaf(x1.y, w.y, acc[5][1]);
      acc[5][2] = fmaf(x1.y, w.z, acc[5][2]); acc[5][3] = fmaf(x1.y, w.w, acc[5][3]);
      acc[6][0] = fmaf(x1.z, w.x, acc[6][0]); acc[6][1] = fmaf(x1.z, w.y, acc[6][1]);
      acc[6][2] = fmaf(x1.z, w.z, acc[6][2]); acc[6][3] = fmaf(x1.z, w.w, acc[6][3]);
      acc[7][0] = fmaf(x1.w, w.x, acc[7][0]); acc[7][1] = fmaf(x1.w, w.y, acc[7][1]);
      acc[7][2] = fmaf(x1.w, w.z, acc[7][2]); acc[7][3] = fmaf(x1.w, w.w, acc[7][3]);
    }
    __syncthreads();
  }

  float* p = part + (size_t)blk * 8192;
#pragma unroll
  for (int r = 0; r < 8; ++r) {
    float4 v;
    v.x = acc[r][0]; v.y = acc[r][1]; v.z = acc[r][2]; v.w = acc[r][3];
    *(float4*)&p[(xrow0 + r) * 128 + 4 * cg] = v;
  }
}

// ---------------- K2a: stage-A partial reduction (float4) ----------------
__global__ __launch_bounds__(256) void k_reduceA(
    const float* __restrict__ part, float* __restrict__ part2, int per_chunk) {
  const int j4 = (blockIdx.x & 7) * 256 + threadIdx.x;  // 0..2047
  const int ch = blockIdx.x >> 3;                       // 0..RCHUNKS-1
  const float4* p = (const float4*)part + (size_t)ch * per_chunk * 2048 + j4;
  float4 s = {0.f, 0.f, 0.f, 0.f};
  for (int b = 0; b < per_chunk; ++b) {
    const float4 v = p[(size_t)b * 2048];
    s.x += v.x; s.y += v.y; s.z += v.z; s.w += v.w;
  }
  ((float4*)part2)[(size_t)ch * 2048 + j4] = s;
}

// ---------------- K2b+K3+K4c fused: final reduce + bias + normalize + l_pos + dot + d0 ----
// 32 blocks x 128 threads; block b handles batch b end-to-end.
__device__ __forceinline__ float red128(float* red, int c, float v) {
  red[c] = v; __syncthreads();
#pragma unroll
  for (int s = 64; s >= 1; s >>= 1) {
    if (c < s) red[c] += red[c + s];
    __syncthreads();
  }
  const float r = red[0];
  __syncthreads();
  return r;
}

__global__ __launch_bounds__(128) void k_fused(
    const float* __restrict__ part2,
    const float* __restrict__ bq, const float* __restrict__ bk,
    const float* __restrict__ queue, const float* __restrict__ cn,
    float* __restrict__ lpos, float* __restrict__ dotq, float* __restrict__ d0) {
  __shared__ float red[128];
  __shared__ float sqv[128];
  const int b = blockIdx.x, c = threadIdx.x;

  // final split-K reduction + bias (deterministic fixed order)
  float zq = 0.f, zk = 0.f;
#pragma unroll
  for (int ch = 0; ch < RCHUNKS; ++ch) {
    zq += part2[(size_t)ch * 8192 + b * 128 + c];
    zk += part2[(size_t)ch * 8192 + (b + 32) * 128 + c];
  }
  zq += bq[c];
  zk += fmaf(MM, bk[c], ONE_MM * bq[c]);

  // normalize
  const float nq = sqrtf(red128(red, c, zq * zq));
  const float nk = sqrtf(red128(red, c, zk * zk));
  const float qv = zq / fmaxf(nq, 1e-12f);
  const float kv = zk / fmaxf(nk, 1e-12f);
  const float qq = red128(red, c, qv * qv);
  const float lp = red128(red, c, qv * kv);
  if (c == 0) lpos[b] = lp;
  sqv[c] = qv;
  __syncthreads();

  // q . queue and q-to-queue distances
  float g[4];
#pragma unroll
  for (int u = 0; u < 4; ++u) g[u] = 0.f;
  for (int c2 = 0; c2 < FEATN; ++c2) {
    const float q2 = sqv[c2];                 // LDS broadcast
    const float* row = queue + c2 * KQ;
#pragma unroll
    for (int u = 0; u < 4; ++u) g[u] = fmaf(q2, row[u * 128 + c], g[u]);
  }
#pragma unroll
  for (int u = 0; u < 4; ++u) {
    const int j = u * 128 + c;
    dotq[b * KQ + j] = g[u];
    const float d2 = qq + cn[j] - 2.f * g[u];
    d0[b * KQ + j] = sqrtf(fmaxf(d2, 0.f));
  }
}

// ---------------- K4a: queue column squared norms ----------------
__global__ __launch_bounds__(256) void k_colnorm(const float* __restrict__ queue,
                                                 float* __restrict__ cn) {
  const int j = blockIdx.x * 256 + threadIdx.x;  // 0..511
  float s = 0.f;
  for (int c = 0; c < FEATN; ++c) { const float t = queue[c * KQ + j]; s = fmaf(t, t, s); }
  cn[j] = s;
}

// ---------------- K4b: queue-queue distances (batch independent) ----------------
__global__ __launch_bounds__(64) void k_dqq(const float* __restrict__ queue,
                                            const float* __restrict__ cn,
                                            float* __restrict__ Dqq) {
  const int i = blockIdx.x, t = threadIdx.x;
  float g[8];
#pragma unroll
  for (int u = 0; u < 8; ++u) g[u] = 0.f;
  for (int c = 0; c < FEATN; ++c) {
    const float qi = queue[c * KQ + i];  // uniform -> scalar
    const float* row = queue + c * KQ;
#pragma unroll
    for (int u = 0; u < 8; ++u) g[u] = fmaf(qi, row[u * 64 + t], g[u]);
  }
  const float cni = cn[i];
#pragma unroll
  for (int u = 0; u < 8; ++u) {
    const int j = u * 64 + t;
    const float d2 = cni + cn[j] - 2.f * g[u];
    Dqq[i * KQ + j] = sqrtf(fmaxf(d2, 0.f));
  }
}

// ---------------- K5: per-row top-5-largest, one WAVE per row ----------------
__global__ __launch_bounds__(256) void k_top5w(
    const float* __restrict__ d0, const float* __restrict__ Dqq,
    int* __restrict__ ej, float* __restrict__ ew) {
  const int wid = (blockIdx.x * 256 + threadIdx.x) >> 6;  // row id 0..16415
  const int lane = threadIdx.x & 63;
  if (wid >= BSZ * NN) return;
  const int b = wid / NN, i = wid % NN;
  const float* d0b = d0 + b * KQ;
  const float* Drow = Dqq + (size_t)(i > 0 ? i - 1 : 0) * KQ;

  unsigned long long key[9];
#pragma unroll
  for (int u = 0; u < 9; ++u) {
    const int j = lane + 64 * u;
    const bool valid = (j < NN);
    float vv = 0.f;
    if (valid) {
      if (i == 0) vv = (j == 0) ? 0.f : d0b[j - 1];
      else if (j == 0) vv = d0b[i - 1];
      else vv = Drow[j - 1];
    }
    key[u] = valid
        ? (((unsigned long long)__float_as_uint(vv) << 32) | (unsigned)j)
        : 0ULL;
  }

  unsigned long long r0, r1, r2, r3, r4;
#pragma unroll
  for (int r = 0; r < 5; ++r) {
    unsigned long long m = key[0];
#pragma unroll
    for (int u = 1; u < 9; ++u) m = (key[u] > m) ? key[u] : m;
#pragma unroll
    for (int s = 1; s < 64; s <<= 1) {
      const unsigned long long o = __shfl_xor(m, s, 64);
      m = (o > m) ? o : m;
    }
    if (r == 0) r0 = m; else if (r == 1) r1 = m; else if (r == 2) r2 = m;
    else if (r == 3) r3 = m; else r4 = m;
#pragma unroll
    for (int u = 0; u < 9; ++u) if (key[u] == m) key[u] = 0ULL;
  }

  if (lane < 5) {
    unsigned long long m = r0;
    if (lane == 1) m = r1;
    else if (lane == 2) m = r2;
    else if (lane == 3) m = r3;
    else if (lane == 4) m = r4;
    const float v = __uint_as_float((unsigned)(m >> 32));
    const int idx = (int)(unsigned)(m & 0xffffffffu);
    const int base = wid * 5 + lane;
    ej[base] = (v > 0.f) ? idx : -1;
    ew[base] = v;
  }
}

// ---------------- K6: SSSP (512 threads, 2 barriers/pass, monotone counter) ----------------
__global__ __launch_bounds__(512) void k_sssp(
    const int* __restrict__ ej, const float* __restrict__ ew,
    float* __restrict__ distout) {
  const int b = blockIdx.x, tid = threadIdx.x;
  __shared__ int dbits[NN];
  __shared__ int sej[NE];
  __shared__ float sew[NE];
  __shared__ int nupd;   // monotone increasing update counter
  for (int e = tid; e < NE; e += 512) { sej[e] = ej[b * NE + e]; sew[e] = ew[b * NE + e]; }
  for (int i = tid; i < NN; i += 512) dbits[i] = (i == 0) ? 0 : 0x7f800000;
  if (tid == 0) nupd = 0;
  __syncthreads();
  int prev = 0;
  for (int it = 0; it < 600; ++it) {
    int any = 0;
    for (int e = tid; e < NE; e += 512) {
      const int dst = sej[e];
      if (dst < 0) continue;
      const int sb = dbits[e / 5];
      if (sb == 0x7f800000) continue;
      const float cand = __int_as_float(sb) + sew[e];
      const int cb = __float_as_int(cand);  // nonneg floats: int order == float order
      if (cb < dbits[dst]) { atomicMin(&dbits[dst], cb); any = 1; }
    }
    if (any) atomicAdd(&nupd, 1);
    __syncthreads();               // all relaxes + counter adds visible
    const int cur = nupd;
    if (cur == prev) break;        // uniform: pass had zero candidate relaxations
    prev = cur;
    __syncthreads();               // protect cur reads from next pass's adds
  }
  for (int i = tid; i < KQ; i += 512) distout[b * KQ + i] = __int_as_float(dbits[i + 1]);
}

// ---------------- K7: global max, weights, logits, labels ----------------
__global__ __launch_bounds__(512) void k_final(
    const float* __restrict__ dist, const float* __restrict__ dotq,
    const float* __restrict__ lpos, float* __restrict__ out) {
  __shared__ float red[512];
  const int tid = threadIdx.x;
  float mx = 0.f;
  for (int idx = tid; idx < BSZ * KQ; idx += 512) {
    const float d = dist[idx];
    if (d != __builtin_inff()) mx = fmaxf(mx, d);
  }
  red[tid] = mx; __syncthreads();
#pragma unroll
  for (int s = 256; s >= 1; s >>= 1) {
    if (tid < s) red[tid] = fmaxf(red[tid], red[tid + s]);
    __syncthreads();
  }
  const float MX = red[0];
  for (int idx = tid; idx < BSZ * KQ; idx += 512) {
    float d = dist[idx];
    if (d == __builtin_inff()) d = MX + 1.f;
    const float w = 1.f / (1.f + d);
    const int b = idx >> 9, j = idx & 511;
    out[b * NN + 1 + j] = dotq[idx] * w / TT;
  }
  if (tid < BSZ) {
    out[tid * NN] = lpos[tid] / TT;   // l_pos column
    out[BSZ * NN + tid] = 0.f;        // labels: int32 zeros == float 0.0f bits
  }
}

// ---------------- launcher ----------------
extern "C" void kernel_launch(void* const* d_in, const int* in_sizes, int n_in,
                              void* d_out, int out_size, void* d_ws, size_t ws_size,
                              hipStream_t stream) {
  const float* Xq    = (const float*)d_in[0];
  const float* Xk    = (const float*)d_in[1];
  const float* Wq    = (const float*)d_in[2];
  const float* bq    = (const float*)d_in[3];
  const float* Wk    = (const float*)d_in[4];
  const float* bk    = (const float*)d_in[5];
  const float* queue = (const float*)d_in[6];
  float* out = (float*)d_out;
  float* ws = (float*)d_ws;

  const size_t fixed_elems =
      RCHUNKS * 8192 + 512 + 32 + 262144 + 16384 * 3 + 82080 * 2;
  // split-K block count: chunk = DIN/nblk must be a multiple of KT=64,
  // nblk must be a multiple of RCHUNKS. Candidates sized to fit ws.
  const int cand[3] = {784, 112, 16};
  int nblk = 16;
  for (int ci = 0; ci < 3; ++ci) {
    if (((size_t)cand[ci] * 8192 + fixed_elems) * 4 <= ws_size) { nblk = cand[ci]; break; }
  }
  const int chunk = DIN / nblk;  // 64 / 448 / 3136
  const int per_chunk = nblk / RCHUNKS;

  float* part = ws;
  float* base = ws + (size_t)nblk * 8192;
  float* part2 = base;                   // RCHUNKS * 8192
  float* cn   = part2 + RCHUNKS * 8192;  // 512
  float* lpos = cn + 512;                // 32
  float* Dqq  = lpos + 32;               // 262144
  float* dotq = Dqq + 262144;            // 16384
  float* d0   = dotq + 16384;            // 16384
  float* dist = d0 + 16384;              // 16384
  int*   ej   = (int*)(dist + 16384);    // 82080 ints
  float* ew   = (float*)(ej + 82080);    // 82080 floats

  hipLaunchKernelGGL(k_dualgemm, dim3(nblk), dim3(256), 0, stream, Xq, Xk, Wq, Wk, part, chunk);
  hipLaunchKernelGGL(k_reduceA,  dim3(RCHUNKS * 8), dim3(256), 0, stream, part, part2, per_chunk);
  hipLaunchKernelGGL(k_colnorm,  dim3(2),    dim3(256), 0, stream, queue, cn);
  hipLaunchKernelGGL(k_dqq,      dim3(512),  dim3(64),  0, stream, queue, cn, Dqq);
  hipLaunchKernelGGL(k_fused,    dim3(32),   dim3(128), 0, stream, part2, bq, bk, queue, cn, lpos, dotq, d0);
  hipLaunchKernelGGL(k_top5w,    dim3((BSZ * NN * 64 + 255) / 256), dim3(256), 0, stream, d0, Dqq, ej, ew);
  hipLaunchKernelGGL(k_sssp,     dim3(BSZ),  dim3(512), 0, stream, ej, ew, dist);
  hipLaunchKernelGGL(k_final,    dim3(1),    dim3(512), 0, stream, dist, dotq, lpos, out);
}

// Round 8
// 195.840 us; speedup vs baseline: 2.4207x; 1.0638x over previous
//
#include <hip/hip_runtime.h>
#include <math.h>

#define DIN 50176
#define BSZ 32
#define FEATN 128
#define KQ 512
#define NN 513      // KQ + 1
#define NE (NN * 5) // 2565 edges per batch
#define MM 0.999f
#define ONE_MM 0.001f
#define TT 0.07f
#define RCHUNKS 14  // second-level reduction fan-in (nblk=392 -> per_chunk=28)
#define KT 64       // X k-tile per block iteration
#define KW 32       // W k-half staged in LDS

// ---------------- K1: fused dual GEMM, register-tiled, LDS-staged ----------------
// nblk=392, chunk=128 (T=2): halves split-K partial traffic vs nblk=784.
__global__ __launch_bounds__(256) void k_dualgemm(
    const float* __restrict__ Xq, const float* __restrict__ Xk,
    const float* __restrict__ Wq, const float* __restrict__ Wk,
    float* __restrict__ part, int chunk) {
  __shared__ float xs[KT * 64];     // [k][row]
  __shared__ float wsq[KW * 128];   // [k][c] raw Wq
  __shared__ float ws2[KW * 128];   // [k][c] momentum-combined
  const int tid = threadIdx.x;
  const int blk = blockIdx.x;
  const int k0 = blk * chunk;

  const int cg = tid & 31;
  const int rg = tid >> 5;
  const int xrow0 = rg * 8;
  const float* wsp = (rg < 4) ? wsq : ws2;   // wave-uniform select

  float acc[8][4];
#pragma unroll
  for (int r = 0; r < 8; ++r)
#pragma unroll
    for (int j = 0; j < 4; ++j) acc[r][j] = 0.f;

  const int srow = tid & 63;
  const int sqb = tid >> 6;  // 0..3
  const float* xsrc = (srow < 32) ? (Xq + (size_t)srow * DIN)
                                  : (Xk + (size_t)(srow - 32) * DIN);
  const int wk0 = tid >> 5;        // k = wk0 + 8u
  const int wcq = (tid & 31) * 4;  // c quad

  const int T = chunk / KT;
  for (int t = 0; t < T; ++t) {
    const int kt = k0 + t * KT;

#pragma unroll
    for (int u = 0; u < 4; ++u) {
      const int q = sqb + 4 * u;                       // k-quad 0..15
      const float4 v = *(const float4*)(xsrc + kt + 4 * q);
      xs[(4 * q + 0) * 64 + srow] = v.x;
      xs[(4 * q + 1) * 64 + srow] = v.y;
      xs[(4 * q + 2) * 64 + srow] = v.z;
      xs[(4 * q + 3) * 64 + srow] = v.w;
    }
    float4 aq[4], ak[4];
#pragma unroll
    for (int u = 0; u < 4; ++u) {
      const size_t g = (size_t)(kt + wk0 + 8 * u) * FEATN + wcq;
      aq[u] = *(const float4*)(Wq + g);
      ak[u] = *(const float4*)(Wk + g);
    }
#pragma unroll
    for (int u = 0; u < 4; ++u) {
      const int off = (wk0 + 8 * u) * 128 + wcq;
      *(float4*)&wsq[off] = aq[u];
      float4 w2;
      w2.x = fmaf(MM, ak[u].x, ONE_MM * aq[u].x);
      w2.y = fmaf(MM, ak[u].y, ONE_MM * aq[u].y);
      w2.z = fmaf(MM, ak[u].z, ONE_MM * aq[u].z);
      w2.w = fmaf(MM, ak[u].w, ONE_MM * aq[u].w);
      *(float4*)&ws2[off] = w2;
    }
    __syncthreads();

#pragma unroll
    for (int u = 0; u < 4; ++u) {
      const size_t g = (size_t)(kt + KW + wk0 + 8 * u) * FEATN + wcq;
      aq[u] = *(const float4*)(Wq + g);
      ak[u] = *(const float4*)(Wk + g);
    }

#pragma unroll 4
    for (int kk = 0; kk < KW; ++kk) {
      const float4 x0 = *(const float4*)&xs[kk * 64 + xrow0];
      const float4 x1 = *(const float4*)&xs[kk * 64 + xrow0 + 4];
      const float4 w = *(const float4*)&wsp[kk * 128 + 4 * cg];
      acc[0][0] = fmaf(x0.x, w.x, acc[0][0]); acc[0][1] = fmaf(x0.x, w.y, acc[0][1]);
      acc[0][2] = fmaf(x0.x, w.z, acc[0][2]); acc[0][3] = fmaf(x0.x, w.w, acc[0][3]);
      acc[1][0] = fmaf(x0.y, w.x, acc[1][0]); acc[1][1] = fmaf(x0.y, w.y, acc[1][1]);
      acc[1][2] = fmaf(x0.y, w.z, acc[1][2]); acc[1][3] = fmaf(x0.y, w.w, acc[1][3]);
      acc[2][0] = fmaf(x0.z, w.x, acc[2][0]); acc[2][1] = fmaf(x0.z, w.y, acc[2][1]);
      acc[2][2] = fmaf(x0.z, w.z, acc[2][2]); acc[2][3] = fmaf(x0.z, w.w, acc[2][3]);
      acc[3][0] = fmaf(x0.w, w.x, acc[3][0]); acc[3][1] = fmaf(x0.w, w.y, acc[3][1]);
      acc[3][2] = fmaf(x0.w, w.z, acc[3][2]); acc[3][3] = fmaf(x0.w, w.w, acc[3][3]);
      acc[4][0] = fmaf(x1.x, w.x, acc[4][0]); acc[4][1] = fmaf(x1.x, w.y, acc[4][1]);
      acc[4][2] = fmaf(x1.x, w.z, acc[4][2]); acc[4][3] = fmaf(x1.x, w.w, acc[4][3]);
      acc[5][0] = fmaf(x1.y, w.x, acc[5][0]); acc[5][1] = fmaf(x1.y, w.y, acc[5][1]);
      acc[5][2] = fmaf(x1.y, w.z, acc[5][2]); acc[5][3] = fmaf(x1.y, w.w, acc[5][3]);
      acc[6][0] = fmaf(x1.z, w.x, acc[6][0]); acc[6][1] = fmaf(x1.z, w.y, acc[6][1]);
      acc[6][2] = fmaf(x1.z, w.z, acc[6][2]); acc[6][3] = fmaf(x1.z, w.w, acc[6][3]);
      acc[7][0] = fmaf(x1.w, w.x, acc[7][0]); acc[7][1] = fmaf(x1.w, w.y, acc[7][1]);
      acc[7][2] = fmaf(x1.w, w.z, acc[7][2]); acc[7][3] = fmaf(x1.w, w.w, acc[7][3]);
    }
    __syncthreads();

#pragma unroll
    for (int u = 0; u < 4; ++u) {
      const int off = (wk0 + 8 * u) * 128 + wcq;
      *(float4*)&wsq[off] = aq[u];
      float4 w2;
      w2.x = fmaf(MM, ak[u].x, ONE_MM * aq[u].x);
      w2.y = fmaf(MM, ak[u].y, ONE_MM * aq[u].y);
      w2.z = fmaf(MM, ak[u].z, ONE_MM * aq[u].z);
      w2.w = fmaf(MM, ak[u].w, ONE_MM * aq[u].w);
      *(float4*)&ws2[off] = w2;
    }
    __syncthreads();

#pragma unroll 4
    for (int kk = 0; kk < KW; ++kk) {
      const float4 x0 = *(const float4*)&xs[(KW + kk) * 64 + xrow0];
      const float4 x1 = *(const float4*)&xs[(KW + kk) * 64 + xrow0 + 4];
      const float4 w = *(const float4*)&wsp[kk * 128 + 4 * cg];
      acc[0][0] = fmaf(x0.x, w.x, acc[0][0]); acc[0][1] = fmaf(x0.x, w.y, acc[0][1]);
      acc[0][2] = fmaf(x0.x, w.z, acc[0][2]); acc[0][3] = fmaf(x0.x, w.w, acc[0][3]);
      acc[1][0] = fmaf(x0.y, w.x, acc[1][0]); acc[1][1] = fmaf(x0.y, w.y, acc[1][1]);
      acc[1][2] = fmaf(x0.y, w.z, acc[1][2]); acc[1][3] = fmaf(x0.y, w.w, acc[1][3]);
      acc[2][0] = fmaf(x0.z, w.x, acc[2][0]); acc[2][1] = fmaf(x0.z, w.y, acc[2][1]);
      acc[2][2] = fmaf(x0.z, w.z, acc[2][2]); acc[2][3] = fmaf(x0.z, w.w, acc[2][3]);
      acc[3][0] = fmaf(x0.w, w.x, acc[3][0]); acc[3][1] = fmaf(x0.w, w.y, acc[3][1]);
      acc[3][2] = fmaf(x0.w, w.z, acc[3][2]); acc[3][3] = fmaf(x0.w, w.w, acc[3][3]);
      acc[4][0] = fmaf(x1.x, w.x, acc[4][0]); acc[4][1] = fmaf(x1.x, w.y, acc[4][1]);
      acc[4][2] = fmaf(x1.x, w.z, acc[4][2]); acc[4][3] = fmaf(x1.x, w.w, acc[4][3]);
      acc[5][0] = fmaf(x1.y, w.x, acc[5][0]); acc[5][1] = fmaf(x1.y, w.y, acc[5][1]);
      acc[5][2] = fmaf(x1.y, w.z, acc[5][2]); acc[5][3] = fmaf(x1.y, w.w, acc[5][3]);
      acc[6][0] = fmaf(x1.z, w.x, acc[6][0]); acc[6][1] = fmaf(x1.z, w.y, acc[6][1]);
      acc[6][2] = fmaf(x1.z, w.z, acc[6][2]); acc[6][3] = fmaf(x1.z, w.w, acc[6][3]);
      acc[7][0] = fmaf(x1.w, w.x, acc[7][0]); acc[7][1] = fmaf(x1.w, w.y, acc[7][1]);
      acc[7][2] = fmaf(x1.w, w.z, acc[7][2]); acc[7][3] = fmaf(x1.w, w.w, acc[7][3]);
    }
    __syncthreads();
  }

  float* p = part + (size_t)blk * 8192;
#pragma unroll
  for (int r = 0; r < 8; ++r) {
    float4 v;
    v.x = acc[r][0]; v.y = acc[r][1]; v.z = acc[r][2]; v.w = acc[r][3];
    *(float4*)&p[(xrow0 + r) * 128 + 4 * cg] = v;
  }
}

// ---------------- K2a: stage-A partial reduction (float4) ----------------
__global__ __launch_bounds__(256) void k_reduceA(
    const float* __restrict__ part, float* __restrict__ part2, int per_chunk) {
  const int j4 = (blockIdx.x & 7) * 256 + threadIdx.x;  // 0..2047
  const int ch = blockIdx.x >> 3;                       // 0..RCHUNKS-1
  const float4* p = (const float4*)part + (size_t)ch * per_chunk * 2048 + j4;
  float4 s = {0.f, 0.f, 0.f, 0.f};
  for (int b = 0; b < per_chunk; ++b) {
    const float4 v = p[(size_t)b * 2048];
    s.x += v.x; s.y += v.y; s.z += v.z; s.w += v.w;
  }
  ((float4*)part2)[(size_t)ch * 2048 + j4] = s;
}

// ---------------- K2b+K3+K4c fused: final reduce + bias + normalize + l_pos + dot + d0 ----
__device__ __forceinline__ float red128(float* red, int c, float v) {
  red[c] = v; __syncthreads();
#pragma unroll
  for (int s = 64; s >= 1; s >>= 1) {
    if (c < s) red[c] += red[c + s];
    __syncthreads();
  }
  const float r = red[0];
  __syncthreads();
  return r;
}

__global__ __launch_bounds__(128) void k_fused(
    const float* __restrict__ part2,
    const float* __restrict__ bq, const float* __restrict__ bk,
    const float* __restrict__ queue, const float* __restrict__ cn,
    float* __restrict__ lpos, float* __restrict__ dotq, float* __restrict__ d0) {
  __shared__ float red[128];
  __shared__ float sqv[128];
  const int b = blockIdx.x, c = threadIdx.x;

  float zq = 0.f, zk = 0.f;
#pragma unroll
  for (int ch = 0; ch < RCHUNKS; ++ch) {
    zq += part2[(size_t)ch * 8192 + b * 128 + c];
    zk += part2[(size_t)ch * 8192 + (b + 32) * 128 + c];
  }
  zq += bq[c];
  zk += fmaf(MM, bk[c], ONE_MM * bq[c]);

  const float nq = sqrtf(red128(red, c, zq * zq));
  const float nk = sqrtf(red128(red, c, zk * zk));
  const float qv = zq / fmaxf(nq, 1e-12f);
  const float kv = zk / fmaxf(nk, 1e-12f);
  const float qq = red128(red, c, qv * qv);
  const float lp = red128(red, c, qv * kv);
  if (c == 0) lpos[b] = lp;
  sqv[c] = qv;
  __syncthreads();

  float g[4];
#pragma unroll
  for (int u = 0; u < 4; ++u) g[u] = 0.f;
  for (int c2 = 0; c2 < FEATN; ++c2) {
    const float q2 = sqv[c2];                 // LDS broadcast
    const float* row = queue + c2 * KQ;
#pragma unroll
    for (int u = 0; u < 4; ++u) g[u] = fmaf(q2, row[u * 128 + c], g[u]);
  }
#pragma unroll
  for (int u = 0; u < 4; ++u) {
    const int j = u * 128 + c;
    dotq[b * KQ + j] = g[u];
    const float d2 = qq + cn[j] - 2.f * g[u];
    d0[b * KQ + j] = sqrtf(fmaxf(d2, 0.f));
  }
}

// ---------------- K4b (+colnorm fused): queue-queue distances, writes cn ----------------
// Per-thread sq[u] accumulates in the SAME fmaf order as the old colnorm kernel,
// so cn values and Dqq are bitwise identical. Self-distance stays exactly 0
// (g[u] == sq[u] for j == i).
__global__ __launch_bounds__(64) void k_dqq(const float* __restrict__ queue,
                                            float* __restrict__ cn,
                                            float* __restrict__ Dqq) {
  __shared__ float scni;
  const int i = blockIdx.x, t = threadIdx.x;
  float g[8], sq[8];
#pragma unroll
  for (int u = 0; u < 8; ++u) { g[u] = 0.f; sq[u] = 0.f; }
  for (int c = 0; c < FEATN; ++c) {
    const float qi = queue[c * KQ + i];  // uniform -> scalar
    const float* row = queue + c * KQ;
#pragma unroll
    for (int u = 0; u < 8; ++u) {
      const float rj = row[u * 64 + t];
      g[u] = fmaf(qi, rj, g[u]);
      sq[u] = fmaf(rj, rj, sq[u]);
    }
  }
  if (t == (i & 63)) {
    const float v = sq[i >> 6];
    scni = v;
    cn[i] = v;          // block i owns column i's norm
  }
  __syncthreads();
  const float cni = scni;
#pragma unroll
  for (int u = 0; u < 8; ++u) {
    const int j = u * 64 + t;
    const float d2 = cni + sq[u] - 2.f * g[u];
    Dqq[i * KQ + j] = sqrtf(fmaxf(d2, 0.f));
  }
}

// ---------------- K5: per-row top-5-largest, one WAVE per row ----------------
__global__ __launch_bounds__(256) void k_top5w(
    const float* __restrict__ d0, const float* __restrict__ Dqq,
    int* __restrict__ ej, float* __restrict__ ew) {
  const int wid = (blockIdx.x * 256 + threadIdx.x) >> 6;  // row id 0..16415
  const int lane = threadIdx.x & 63;
  if (wid >= BSZ * NN) return;
  const int b = wid / NN, i = wid % NN;
  const float* d0b = d0 + b * KQ;
  const float* Drow = Dqq + (size_t)(i > 0 ? i - 1 : 0) * KQ;

  unsigned long long key[9];
#pragma unroll
  for (int u = 0; u < 9; ++u) {
    const int j = lane + 64 * u;
    const bool valid = (j < NN);
    float vv = 0.f;
    if (valid) {
      if (i == 0) vv = (j == 0) ? 0.f : d0b[j - 1];
      else if (j == 0) vv = d0b[i - 1];
      else vv = Drow[j - 1];
    }
    key[u] = valid
        ? (((unsigned long long)__float_as_uint(vv) << 32) | (unsigned)j)
        : 0ULL;
  }

  unsigned long long r0, r1, r2, r3, r4;
#pragma unroll
  for (int r = 0; r < 5; ++r) {
    unsigned long long m = key[0];
#pragma unroll
    for (int u = 1; u < 9; ++u) m = (key[u] > m) ? key[u] : m;
#pragma unroll
    for (int s = 1; s < 64; s <<= 1) {
      const unsigned long long o = __shfl_xor(m, s, 64);
      m = (o > m) ? o : m;
    }
    if (r == 0) r0 = m; else if (r == 1) r1 = m; else if (r == 2) r2 = m;
    else if (r == 3) r3 = m; else r4 = m;
#pragma unroll
    for (int u = 0; u < 9; ++u) if (key[u] == m) key[u] = 0ULL;
  }

  if (lane < 5) {
    unsigned long long m = r0;
    if (lane == 1) m = r1;
    else if (lane == 2) m = r2;
    else if (lane == 3) m = r3;
    else if (lane == 4) m = r4;
    const float v = __uint_as_float((unsigned)(m >> 32));
    const int idx = (int)(unsigned)(m & 0xffffffffu);
    const int base = wid * 5 + lane;
    ej[base] = (v > 0.f) ? idx : -1;
    ew[base] = v;
  }
}

// ---------------- K6: SSSP (512 threads, 2 barriers/pass, monotone counter) ----------------
__global__ __launch_bounds__(512) void k_sssp(
    const int* __restrict__ ej, const float* __restrict__ ew,
    float* __restrict__ distout) {
  const int b = blockIdx.x, tid = threadIdx.x;
  __shared__ int dbits[NN];
  __shared__ int sej[NE];
  __shared__ float sew[NE];
  __shared__ int nupd;   // monotone increasing update counter
  for (int e = tid; e < NE; e += 512) { sej[e] = ej[b * NE + e]; sew[e] = ew[b * NE + e]; }
  for (int i = tid; i < NN; i += 512) dbits[i] = (i == 0) ? 0 : 0x7f800000;
  if (tid == 0) nupd = 0;
  __syncthreads();
  int prev = 0;
  for (int it = 0; it < 600; ++it) {
    int any = 0;
    for (int e = tid; e < NE; e += 512) {
      const int dst = sej[e];
      if (dst < 0) continue;
      const int sb = dbits[e / 5];
      if (sb == 0x7f800000) continue;
      const float cand = __int_as_float(sb) + sew[e];
      const int cb = __float_as_int(cand);  // nonneg floats: int order == float order
      if (cb < dbits[dst]) { atomicMin(&dbits[dst], cb); any = 1; }
    }
    if (any) atomicAdd(&nupd, 1);
    __syncthreads();               // all relaxes + counter adds visible
    const int cur = nupd;
    if (cur == prev) break;        // uniform: pass had zero candidate relaxations
    prev = cur;
    __syncthreads();               // protect cur reads from next pass's adds
  }
  for (int i = tid; i < KQ; i += 512) distout[b * KQ + i] = __int_as_float(dbits[i + 1]);
}

// ---------------- K7: global max, weights, logits, labels ----------------
__global__ __launch_bounds__(512) void k_final(
    const float* __restrict__ dist, const float* __restrict__ dotq,
    const float* __restrict__ lpos, float* __restrict__ out) {
  __shared__ float red[512];
  const int tid = threadIdx.x;
  float mx = 0.f;
  for (int idx = tid; idx < BSZ * KQ; idx += 512) {
    const float d = dist[idx];
    if (d != __builtin_inff()) mx = fmaxf(mx, d);
  }
  red[tid] = mx; __syncthreads();
#pragma unroll
  for (int s = 256; s >= 1; s >>= 1) {
    if (tid < s) red[tid] = fmaxf(red[tid], red[tid + s]);
    __syncthreads();
  }
  const float MX = red[0];
  for (int idx = tid; idx < BSZ * KQ; idx += 512) {
    float d = dist[idx];
    if (d == __builtin_inff()) d = MX + 1.f;
    const float w = 1.f / (1.f + d);
    const int b = idx >> 9, j = idx & 511;
    out[b * NN + 1 + j] = dotq[idx] * w / TT;
  }
  if (tid < BSZ) {
    out[tid * NN] = lpos[tid] / TT;   // l_pos column
    out[BSZ * NN + tid] = 0.f;        // labels: int32 zeros == float 0.0f bits
  }
}

// ---------------- launcher ----------------
extern "C" void kernel_launch(void* const* d_in, const int* in_sizes, int n_in,
                              void* d_out, int out_size, void* d_ws, size_t ws_size,
                              hipStream_t stream) {
  const float* Xq    = (const float*)d_in[0];
  const float* Xk    = (const float*)d_in[1];
  const float* Wq    = (const float*)d_in[2];
  const float* bq    = (const float*)d_in[3];
  const float* Wk    = (const float*)d_in[4];
  const float* bk    = (const float*)d_in[5];
  const float* queue = (const float*)d_in[6];
  float* out = (float*)d_out;
  float* ws = (float*)d_ws;

  const size_t fixed_elems =
      RCHUNKS * 8192 + 512 + 32 + 262144 + 16384 * 3 + 82080 * 2;
  // split-K block count: chunk = DIN/nblk must be a multiple of KT=64,
  // nblk must be a multiple of RCHUNKS=14. Candidates sized to fit ws.
  const int cand[3] = {392, 98, 14};
  int nblk = 14;
  for (int ci = 0; ci < 3; ++ci) {
    if (((size_t)cand[ci] * 8192 + fixed_elems) * 4 <= ws_size) { nblk = cand[ci]; break; }
  }
  const int chunk = DIN / nblk;  // 128 / 512 / 3584
  const int per_chunk = nblk / RCHUNKS;

  float* part = ws;
  float* base = ws + (size_t)nblk * 8192;
  float* part2 = base;                   // RCHUNKS * 8192
  float* cn   = part2 + RCHUNKS * 8192;  // 512
  float* lpos = cn + 512;                // 32
  float* Dqq  = lpos + 32;               // 262144
  float* dotq = Dqq + 262144;            // 16384
  float* d0   = dotq + 16384;            // 16384
  float* dist = d0 + 16384;              // 16384
  int*   ej   = (int*)(dist + 16384);    // 82080 ints
  float* ew   = (float*)(ej + 82080);    // 82080 floats

  hipLaunchKernelGGL(k_dualgemm, dim3(nblk), dim3(256), 0, stream, Xq, Xk, Wq, Wk, part, chunk);
  hipLaunchKernelGGL(k_reduceA,  dim3(RCHUNKS * 8), dim3(256), 0, stream, part, part2, per_chunk);
  hipLaunchKernelGGL(k_dqq,      dim3(512),  dim3(64),  0, stream, queue, cn, Dqq);
  hipLaunchKernelGGL(k_fused,    dim3(32),   dim3(128), 0, stream, part2, bq, bk, queue, cn, lpos, dotq, d0);
  hipLaunchKernelGGL(k_top5w,    dim3((BSZ * NN * 64 + 255) / 256), dim3(256), 0, stream, d0, Dqq, ej, ew);
  hipLaunchKernelGGL(k_sssp,     dim3(BSZ),  dim3(512), 0, stream, ej, ew, dist);
  hipLaunchKernelGGL(k_final,    dim3(1),    dim3(512), 0, stream, dist, dotq, lpos, out);
}